// Round 2
// baseline (22112.581 us; speedup 1.0000x reference)
//
#include <hip/hip_runtime.h>
#include <math.h>

// ---- problem constants ----
#define BB   8
#define TT   5
#define NN   2048
#define FIN  64
#define EE   32768
#define DD   256
#define HH   8
#define FFD  2048
#define NCLS 10
#define GG   (BB*TT)        // 40 graphs
#define BN   (BB*NN)        // 16384
#define NM   (GG*NN)        // 81920 rows (= TT*BN)

// ---- chunking ----
#define GC        4               // graphs per conv chunk (10 chunks)
#define CONV_ROWS (GC*NN)         // 8192
#define CONV_EDGES (GC*EE)        // 131072
#define MC        2048            // bn per temporal-attention chunk (8 chunks)
#define MR        16384           // rows per proj/FFN chunk (5 chunks)

// ---- ordered-int float max helpers ----
__device__ __forceinline__ unsigned f2ord(float f) {
    int i = __float_as_int(f);
    return (unsigned)i ^ (((unsigned)(i >> 31)) | 0x80000000u);
}
__device__ __forceinline__ float ord2f(unsigned u) {
    int i = (u & 0x80000000u) ? (int)(u ^ 0x80000000u) : (int)~u;
    return __int_as_float(i);
}

// =====================================================================
// Generic tiled fp32 GEMM: C[M x Nc](ldc) = A[M x K](lda) @ W[:, wcol0..](ldw) + bias
// 64x64 tile, BK=16, 256 threads, 4x4 per thread. M%64==0, Nc%64==0, K%16==0.
// =====================================================================
template <bool RELU, bool ACCUM>
__global__ __launch_bounds__(256) void gemm64(
    const float* __restrict__ A, int lda,
    const float* __restrict__ W, int ldw, int wcol0,
    const float* __restrict__ bias,
    float* __restrict__ C, int ldc, int K)
{
    __shared__ float As[16][64];
    __shared__ float Bs[16][64];
    const int tid = threadIdx.x;
    const int tx = tid & 15, ty = tid >> 4;
    const int row0 = blockIdx.x * 64;
    const int col0 = blockIdx.y * 64;
    float acc[4][4] = {};
    for (int k0 = 0; k0 < K; k0 += 16) {
#pragma unroll
        for (int i = 0; i < 4; ++i) {
            int idx = tid + i * 256;
            int m = idx >> 4, kk = idx & 15;
            As[kk][m] = A[(long)(row0 + m) * lda + k0 + kk];
        }
#pragma unroll
        for (int i = 0; i < 4; ++i) {
            int idx = tid + i * 256;
            int kk = idx >> 6, n = idx & 63;
            Bs[kk][n] = W[(long)(k0 + kk) * ldw + wcol0 + col0 + n];
        }
        __syncthreads();
#pragma unroll
        for (int kk = 0; kk < 16; ++kk) {
            float a[4], b[4];
#pragma unroll
            for (int i = 0; i < 4; ++i) a[i] = As[kk][ty * 4 + i];
#pragma unroll
            for (int j = 0; j < 4; ++j) b[j] = Bs[kk][tx * 4 + j];
#pragma unroll
            for (int i = 0; i < 4; ++i)
#pragma unroll
                for (int j = 0; j < 4; ++j) acc[i][j] += a[i] * b[j];
        }
        __syncthreads();
    }
#pragma unroll
    for (int i = 0; i < 4; ++i) {
        int r = row0 + ty * 4 + i;
#pragma unroll
        for (int j = 0; j < 4; ++j) {
            int c = col0 + tx * 4 + j;
            float v = acc[i][j];
            if (bias) v += bias[c];
            long o = (long)r * ldc + c;
            if (ACCUM) v += C[o];
            if (RELU) v = fmaxf(v, 0.f);
            C[o] = v;
        }
    }
}

// =====================================================================
// Conv stage (chunk of GC graphs, g0 = first graph). q/k/v/alpha/m/denom are
// chunk-local; eidx/eattr/out use global indices.
// =====================================================================
__global__ void init_md(unsigned* __restrict__ m_ord, float* __restrict__ denom) {
    int gid = blockIdx.x * blockDim.x + threadIdx.x;
    if (gid < CONV_ROWS * HH) { m_ord[gid] = 0u; denom[gid] = 0.f; }
}

__global__ __launch_bounds__(256) void conv_alpha(
    const float* __restrict__ qb, const float* __restrict__ kb,
    const int* __restrict__ eidx, const float* __restrict__ eattr,
    const float* __restrict__ W_edge, const float* __restrict__ b_edge,
    float* __restrict__ alpha, unsigned* __restrict__ m_ord, int g0)
{
    __shared__ float We[6 * 256];
    __shared__ float Be[256];
    const int tid = threadIdx.x;
    for (int i = tid; i < 6 * 256; i += 256) We[i] = W_edge[i];
    Be[tid] = b_edge[tid];
    __syncthreads();
    const int wave = tid >> 6, lane = tid & 63;
    long el = (long)blockIdx.x * 4 + wave;       // chunk-local edge
    int gl = (int)(el / EE), e = (int)(el % EE); // local graph, edge-in-graph
    int g = g0 + gl;
    int src = eidx[((long)g * 2 + 0) * EE + e];
    int tgt = eidx[((long)g * 2 + 1) * EE + e];
    long sf = (long)gl * NN + src;
    long tf = (long)gl * NN + tgt;
    long ge = (long)g * EE + e;
    float ea[6];
#pragma unroll
    for (int j = 0; j < 6; ++j) ea[j] = eattr[ge * 6 + j];
    const float scale = 0.17677669529663687f;  // 1/sqrt(32)
#pragma unroll
    for (int i = 0; i < 4; ++i) {
        int d = lane + 64 * i;
        float ef = Be[d];
#pragma unroll
        for (int j = 0; j < 6; ++j) ef += ea[j] * We[j * 256 + d];
        float p = qb[tf * 256 + d] * (kb[sf * 256 + d] + ef);
#pragma unroll
        for (int m = 16; m >= 1; m >>= 1) p += __shfl_xor(p, m, 64);
        if ((lane & 31) == 0) {
            int h = d >> 5;
            float a = p * scale;
            alpha[el * 8 + h] = a;
            atomicMax(&m_ord[tf * 8 + h], f2ord(a));
        }
    }
}

__global__ void conv_exp(
    const int* __restrict__ eidx, float* __restrict__ alpha,
    const unsigned* __restrict__ m_ord, float* __restrict__ denom, int g0)
{
    long gid = (long)blockIdx.x * blockDim.x + threadIdx.x;
    if (gid >= (long)CONV_EDGES * 8) return;
    long el = gid >> 3;
    int h = (int)(gid & 7);
    int gl = (int)(el / EE), e = (int)(el % EE);
    int tgt = eidx[((long)(g0 + gl) * 2 + 1) * EE + e];
    long tf = (long)gl * NN + tgt;
    float m = ord2f(m_ord[tf * 8 + h]);
    float a = expf(alpha[gid] - m);
    alpha[gid] = a;
    atomicAdd(&denom[tf * 8 + h], a);
}

__global__ __launch_bounds__(256) void conv_agg(
    const float* __restrict__ vb,
    const int* __restrict__ eidx, const float* __restrict__ eattr,
    const float* __restrict__ W_edge, const float* __restrict__ b_edge,
    const float* __restrict__ alpha, const float* __restrict__ denom,
    float* __restrict__ out, int g0)
{
    __shared__ float We[6 * 256];
    __shared__ float Be[256];
    const int tid = threadIdx.x;
    for (int i = tid; i < 6 * 256; i += 256) We[i] = W_edge[i];
    Be[tid] = b_edge[tid];
    __syncthreads();
    const int wave = tid >> 6, lane = tid & 63;
    long el = (long)blockIdx.x * 4 + wave;
    int gl = (int)(el / EE), e = (int)(el % EE);
    int g = g0 + gl;
    int src = eidx[((long)g * 2 + 0) * EE + e];
    int tgt = eidx[((long)g * 2 + 1) * EE + e];
    long sf = (long)gl * NN + src;
    long tf = (long)gl * NN + tgt;
    long ge = (long)g * EE + e;
    float ea[6];
#pragma unroll
    for (int j = 0; j < 6; ++j) ea[j] = eattr[ge * 6 + j];
    float w[8];
#pragma unroll
    for (int h = 0; h < 8; ++h) w[h] = alpha[el * 8 + h] / denom[tf * 8 + h];
    long orow = (long)g * NN + tgt;  // global conv-layout row
#pragma unroll
    for (int i = 0; i < 4; ++i) {
        int d = lane + 64 * i;
        float ef = Be[d];
#pragma unroll
        for (int j = 0; j < 6; ++j) ef += ea[j] * We[j * 256 + d];
        float val = w[d >> 5] * (vb[sf * 256 + d] + ef);
        atomicAdd(&out[orow * 256 + d], val);
    }
}

// [b*T+t][n][256] -> [t*BN + b*N + n][256]  (float4 copy)
__global__ void transpose_bt(const float* __restrict__ in, float* __restrict__ out) {
    long gid = (long)blockIdx.x * blockDim.x + threadIdx.x;  // NM*64 float4s
    long row = gid >> 6;
    int c4 = (int)(gid & 63);
    int n = (int)(row % NN);
    int bt = (int)(row / NN);
    int t = bt % TT, b = bt / TT;
    long orow = (long)t * BN + (long)b * NN + n;
    ((float4*)out)[orow * 64 + c4] = ((const float4*)in)[row * 64 + c4];
}

// temporal attention over T=5 for a chunk of MC nodes; q/k/v in [T][MC][256]
// chunk layout; output written to full seq-layout buffer at bn = c0 + local.
__global__ __launch_bounds__(256) void mha_time(
    const float* __restrict__ qb, const float* __restrict__ kb,
    const float* __restrict__ vb, float* __restrict__ ob, int c0)
{
    const int tid = threadIdx.x;
    const int grp = tid >> 5, c = tid & 31;
    int pair = blockIdx.x * 8 + grp;     // MC*HH pairs
    int h = pair & 7;
    int bnl = pair >> 3;                 // local node idx in chunk
    const float scale = 0.17677669529663687f;
    float q[TT], k[TT], v[TT];
#pragma unroll
    for (int t = 0; t < TT; ++t) {
        long r = ((long)t * MC + bnl) * 256 + h * 32 + c;
        q[t] = qb[r]; k[t] = kb[r]; v[t] = vb[r];
    }
    float s[TT][TT];
#pragma unroll
    for (int t = 0; t < TT; ++t)
#pragma unroll
        for (int u = 0; u < TT; ++u) {
            float p = q[t] * k[u];
#pragma unroll
            for (int m = 16; m >= 1; m >>= 1) p += __shfl_xor(p, m, 64);
            s[t][u] = p * scale;
        }
#pragma unroll
    for (int t = 0; t < TT; ++t) {
        float mx = s[t][0];
#pragma unroll
        for (int u = 1; u < TT; ++u) mx = fmaxf(mx, s[t][u]);
        float sm = 0.f;
#pragma unroll
        for (int u = 0; u < TT; ++u) { s[t][u] = expf(s[t][u] - mx); sm += s[t][u]; }
        float inv = 1.f / sm;
        float o = 0.f;
#pragma unroll
        for (int u = 0; u < TT; ++u) o += s[t][u] * v[u];
        ob[((long)t * BN + c0 + bnl) * 256 + h * 32 + c] = o * inv;
    }
}

// seq = LayerNorm(seq + res) * g + b, rows of 256; one wave per row
__global__ __launch_bounds__(256) void ln_residual(
    float* __restrict__ seq, const float* __restrict__ res,
    const float* __restrict__ g, const float* __restrict__ b)
{
    const int wave = threadIdx.x >> 6, lane = threadIdx.x & 63;
    long row = (long)blockIdx.x * 4 + wave;
    float x[4];
    float sum = 0.f;
#pragma unroll
    for (int i = 0; i < 4; ++i) {
        int d = lane + 64 * i;
        x[i] = seq[row * 256 + d] + res[row * 256 + d];
        sum += x[i];
    }
#pragma unroll
    for (int m = 32; m >= 1; m >>= 1) sum += __shfl_xor(sum, m, 64);
    float mean = sum * (1.f / 256.f);
    float vs = 0.f;
#pragma unroll
    for (int i = 0; i < 4; ++i) { float dl = x[i] - mean; vs += dl * dl; }
#pragma unroll
    for (int m = 32; m >= 1; m >>= 1) vs += __shfl_xor(vs, m, 64);
    float inv = rsqrtf(vs * (1.f / 256.f) + 1e-5f);
#pragma unroll
    for (int i = 0; i < 4; ++i) {
        int d = lane + 64 * i;
        seq[row * 256 + d] = (x[i] - mean) * inv * g[d] + b[d];
    }
}

// out[row][0..9] = seq[t=T-1 rows] @ W_out + b_out ; one block per row
__global__ __launch_bounds__(256) void final_out(
    const float* __restrict__ seq, const float* __restrict__ Wd,
    const float* __restrict__ bd, float* __restrict__ out)
{
    __shared__ float xs[256];
    long row = blockIdx.x;
    xs[threadIdx.x] = seq[((long)(TT - 1) * BN + row) * 256 + threadIdx.x];
    __syncthreads();
    const int wv = threadIdx.x >> 6, lane = threadIdx.x & 63;
    for (int o = wv; o < NCLS; o += 4) {
        float p = 0.f;
#pragma unroll
        for (int i = 0; i < 4; ++i) {
            int kk = lane + 64 * i;
            p += xs[kk] * Wd[kk * NCLS + o];
        }
#pragma unroll
        for (int m = 32; m >= 1; m >>= 1) p += __shfl_xor(p, m, 64);
        if (lane == 0) out[row * NCLS + o] = p + bd[o];
    }
}

// diagnostic sentinel: ws too small
__global__ void fill_sentinel(float* __restrict__ out, int n) {
    int gid = blockIdx.x * blockDim.x + threadIdx.x;
    if (gid < n) out[gid] = 1.0e6f;
}

// =====================================================================
extern "C" void kernel_launch(void* const* d_in, const int* in_sizes, int n_in,
                              void* d_out, int out_size, void* d_ws, size_t ws_size,
                              hipStream_t stream) {
    const float* xseq  = (const float*)d_in[0];
    const int*   eidx  = (const int*)d_in[1];
    const float* eattr = (const float*)d_in[2];
    const float* W_node = (const float*)d_in[3];
    const float* b_node = (const float*)d_in[4];
    const float* W_edge = (const float*)d_in[5];
    const float* b_edge = (const float*)d_in[6];
    const float* Wq = (const float*)d_in[7];  const float* bq = (const float*)d_in[8];
    const float* Wk = (const float*)d_in[9];  const float* bk = (const float*)d_in[10];
    const float* Wv = (const float*)d_in[11]; const float* bv = (const float*)d_in[12];
    const float* Ws = (const float*)d_in[13]; const float* bs = (const float*)d_in[14];
    const float* Wqkv = (const float*)d_in[15]; const float* bqkv = (const float*)d_in[16];
    const float* Wo = (const float*)d_in[17];   const float* bo = (const float*)d_in[18];
    const float* W1 = (const float*)d_in[19];   const float* b1 = (const float*)d_in[20];
    const float* W2 = (const float*)d_in[21];   const float* b2 = (const float*)d_in[22];
    const float* g_ln1 = (const float*)d_in[23]; const float* b_ln1 = (const float*)d_in[24];
    const float* g_ln2 = (const float*)d_in[25]; const float* b_ln2 = (const float*)d_in[26];
    const float* W_out = (const float*)d_in[27]; const float* b_out = (const float*)d_in[28];
    float* out = (float*)d_out;

    // ---- workspace: A (seq, 80MB) + B (ping-pong, 80MB) + S (scratch, 32MB) ----
    const long SZ = (long)NM * DD;            // 20,971,520 floats
    const long SFL = 8388608;                 // 32 MB scratch in floats
    float* A = (float*)d_ws;
    float* Bf = A + SZ;
    float* S = Bf + SZ;
    const size_t need = (size_t)(2 * SZ + SFL) * 4;   // 192 MB
    if (ws_size < need) {                              // diagnostic, not silent
        fill_sentinel<<<dim3((out_size + 255) / 256), dim3(256), 0, stream>>>(out, out_size);
        return;
    }

    dim3 blk(256);

    // ---- stage 1: node embed (A = h), skip (B = h@Ws+bs), conv chunks ----
    gemm64<false, false><<<dim3(NM / 64, DD / 64), blk, 0, stream>>>(
        xseq, FIN, W_node, DD, 0, b_node, A, DD, FIN);
    gemm64<false, false><<<dim3(NM / 64, DD / 64), blk, 0, stream>>>(
        A, DD, Ws, DD, 0, bs, Bf, DD, DD);

    for (int gc = 0; gc < GG / GC; ++gc) {
        const int g0 = gc * GC;
        const long row0 = (long)g0 * NN;
        float* Sq = S;
        float* Sk = Sq + (long)CONV_ROWS * DD;
        float* Sv = Sk + (long)CONV_ROWS * DD;
        float* al = Sv + (long)CONV_ROWS * DD;            // CONV_EDGES*8
        unsigned* mo = (unsigned*)(al + (long)CONV_EDGES * 8);
        float* dn = (float*)(mo + CONV_ROWS * 8);
        gemm64<false, false><<<dim3(CONV_ROWS / 64, DD / 64), blk, 0, stream>>>(
            A + row0 * DD, DD, Wq, DD, 0, bq, Sq, DD, DD);
        gemm64<false, false><<<dim3(CONV_ROWS / 64, DD / 64), blk, 0, stream>>>(
            A + row0 * DD, DD, Wk, DD, 0, bk, Sk, DD, DD);
        gemm64<false, false><<<dim3(CONV_ROWS / 64, DD / 64), blk, 0, stream>>>(
            A + row0 * DD, DD, Wv, DD, 0, bv, Sv, DD, DD);
        init_md<<<dim3(CONV_ROWS * HH / 256), blk, 0, stream>>>(mo, dn);
        conv_alpha<<<dim3(CONV_EDGES / 4), blk, 0, stream>>>(
            Sq, Sk, eidx, eattr, W_edge, b_edge, al, mo, g0);
        conv_exp<<<dim3(CONV_EDGES * 8 / 256), blk, 0, stream>>>(eidx, al, mo, dn, g0);
        conv_agg<<<dim3(CONV_EDGES / 4), blk, 0, stream>>>(
            Sv, eidx, eattr, W_edge, b_edge, al, dn, Bf, g0);
    }

    // ---- reshape to [T, B*N, D]: B -> A ----
    transpose_bt<<<dim3(NM * 64 / 256), blk, 0, stream>>>(Bf, A);

    // ---- stage 2: 3 temporal transformer encoder layers ----
    for (int l = 0; l < 3; ++l) {
        const float* Wl = Wqkv + (long)l * DD * 3 * DD;
        const float* bl = bqkv + (long)l * 3 * DD;
        // qkv + attention, chunked over nodes
        for (int mc = 0; mc < BN / MC; ++mc) {
            const int c0 = mc * MC;
            float* Sq = S;
            float* Sk = Sq + (long)TT * MC * DD;
            float* Sv = Sk + (long)TT * MC * DD;
            for (int t = 0; t < TT; ++t) {
                const float* Arow = A + ((long)t * BN + c0) * DD;
                gemm64<false, false><<<dim3(MC / 64, DD / 64), blk, 0, stream>>>(
                    Arow, DD, Wl, 3 * DD, 0, bl + 0, Sq + (long)t * MC * DD, DD, DD);
                gemm64<false, false><<<dim3(MC / 64, DD / 64), blk, 0, stream>>>(
                    Arow, DD, Wl, 3 * DD, DD, bl + DD, Sk + (long)t * MC * DD, DD, DD);
                gemm64<false, false><<<dim3(MC / 64, DD / 64), blk, 0, stream>>>(
                    Arow, DD, Wl, 3 * DD, 2 * DD, bl + 2 * DD, Sv + (long)t * MC * DD, DD, DD);
            }
            mha_time<<<dim3(MC * HH / 8), blk, 0, stream>>>(Sq, Sk, Sv, Bf, c0);
        }
        // output proj + LN1, row-chunked
        for (int mr = 0; mr < NM / MR; ++mr) {
            const long r0 = (long)mr * MR;
            gemm64<false, false><<<dim3(MR / 64, DD / 64), blk, 0, stream>>>(
                Bf + r0 * DD, DD, Wo + (long)l * DD * DD, DD, 0, bo + (long)l * DD, S, DD, DD);
            ln_residual<<<dim3(MR / 4), blk, 0, stream>>>(
                A + r0 * DD, S, g_ln1 + l * DD, b_ln1 + l * DD);
        }
        // FFN + LN2, row-chunked; hidden chunked 8 x 256
        for (int mr = 0; mr < NM / MR; ++mr) {
            const long r0 = (long)mr * MR;
            float* S1 = S;
            float* S2 = S + (long)MR * DD;
            for (int cch = 0; cch < FFD / DD; ++cch) {
                gemm64<true, false><<<dim3(MR / 64, DD / 64), blk, 0, stream>>>(
                    A + r0 * DD, DD, W1 + (long)l * DD * FFD, FFD, cch * DD,
                    b1 + (long)l * FFD + cch * DD, S1, DD, DD);
                if (cch == 0)
                    gemm64<false, false><<<dim3(MR / 64, DD / 64), blk, 0, stream>>>(
                        S1, DD, W2 + (long)l * FFD * DD + (long)cch * DD * DD, DD, 0,
                        b2 + (long)l * DD, S2, DD, DD);
                else
                    gemm64<false, true><<<dim3(MR / 64, DD / 64), blk, 0, stream>>>(
                        S1, DD, W2 + (long)l * FFD * DD + (long)cch * DD * DD, DD, 0,
                        nullptr, S2, DD, DD);
            }
            ln_residual<<<dim3(MR / 4), blk, 0, stream>>>(
                A + r0 * DD, S2, g_ln2 + l * DD, b_ln2 + l * DD);
        }
    }

    // ---- output head ----
    final_out<<<dim3(BN), blk, 0, stream>>>(A, W_out, b_out, out);
}

// Round 3
// 4828.405 us; speedup vs baseline: 4.5797x; 4.5797x over previous
//
#include <hip/hip_runtime.h>
#include <math.h>

// ---- problem constants ----
#define BB   8
#define TT   5
#define NN   2048
#define FIN  64
#define EE   32768
#define DD   256
#define HH   8
#define FFD  2048
#define NCLS 10
#define GG   (BB*TT)        // 40 graphs
#define BN   (BB*NN)        // 16384
#define NM   (GG*NN)        // 81920 rows (= TT*BN)

// ---- chunking ----
#define GC        4               // graphs per conv chunk (10 chunks)
#define CONV_ROWS (GC*NN)         // 8192
#define CONV_EDGES (GC*EE)        // 131072
#define MR        16384           // rows per FFN chunk (5 chunks)

typedef __attribute__((ext_vector_type(8))) short short8;
typedef __attribute__((ext_vector_type(4))) float f32x4;

// ---- bf16 helpers (RNE) ----
__device__ __forceinline__ unsigned short f2b(float f) {
    unsigned u = __float_as_uint(f);
    u = (u + 0x7fffu + ((u >> 16) & 1u)) >> 16;
    return (unsigned short)u;
}
__device__ __forceinline__ float b2f(unsigned short b) {
    return __uint_as_float(((unsigned)b) << 16);
}

// ---- ordered-int float max helpers ----
__device__ __forceinline__ unsigned f2ord(float f) {
    int i = __float_as_int(f);
    return (unsigned)i ^ (((unsigned)(i >> 31)) | 0x80000000u);
}
__device__ __forceinline__ float ord2f(unsigned u) {
    int i = (u & 0x80000000u) ? (int)(u ^ 0x80000000u) : (int)~u;
    return __int_as_float(i);
}

// =====================================================================
// Weight transpose+convert: in fp32 [K][N] row-major -> out bf16 [N][K]
// =====================================================================
__global__ void wtrans(const float* __restrict__ in, unsigned short* __restrict__ out,
                       int K, int N) {
    __shared__ float t[32][33];
    const int n0 = blockIdx.x * 32, k0 = blockIdx.y * 32;
    const int tx = threadIdx.x, ty = threadIdx.y;
    for (int i = ty; i < 32; i += 8) t[i][tx] = in[(long)(k0 + i) * N + n0 + tx];
    __syncthreads();
    for (int i = ty; i < 32; i += 8)
        out[(long)(n0 + i) * K + k0 + tx] = f2b(t[tx][i]);
}

// fp32 -> bf16 elementwise (n4 float4 groups)
__global__ void xconvert(const float* __restrict__ in, unsigned short* __restrict__ out, long n4) {
    long gid = (long)blockIdx.x * blockDim.x + threadIdx.x;
    if (gid >= n4) return;
    float4 v = ((const float4*)in)[gid];
    ushort4 o;
    o.x = f2b(v.x); o.y = f2b(v.y); o.z = f2b(v.z); o.w = f2b(v.w);
    ((ushort4*)out)[gid] = o;
}

// =====================================================================
// bf16 MFMA GEMM: C[M x N] = A[M x K] @ W[K x N] + bias
// A bf16 row-major (lda), WT = W^T bf16 [N][K], C fp32 or bf16 (ldc).
// 128x128 tile, BK=32, 256 threads = 4 waves (2x2), 16x16x32 MFMA.
// M%128==0, N%128==0, K%32==0.
// =====================================================================
template <bool RELU, bool OUTBF>
__global__ __launch_bounds__(256) void gemm_mfma(
    const unsigned short* __restrict__ A, int lda,
    const unsigned short* __restrict__ WT,
    const float* __restrict__ bias,
    void* __restrict__ Cv, int ldc, int K)
{
    __shared__ unsigned short As[128][40];
    __shared__ unsigned short Bs[128][40];
    const int tid = threadIdx.x;
    const int wid = tid >> 6, lane = tid & 63;
    const int wm = wid >> 1, wn = wid & 1;
    const long row0 = (long)blockIdx.x * 128;
    const long col0 = (long)blockIdx.y * 128;
    const int srow = tid >> 1;            // staging row 0..127
    const int sk = (tid & 1) * 16;        // staging k offset (elements)
    f32x4 acc[4][4] = {};
    const int kb = (lane >> 4) * 8;
    const int fr = lane & 15;
    for (int k0 = 0; k0 < K; k0 += 32) {
        const uint4 ga0 = *(const uint4*)&A[(row0 + srow) * lda + k0 + sk];
        const uint4 ga1 = *(const uint4*)&A[(row0 + srow) * lda + k0 + sk + 8];
        const uint4 gb0 = *(const uint4*)&WT[(col0 + srow) * (long)K + k0 + sk];
        const uint4 gb1 = *(const uint4*)&WT[(col0 + srow) * (long)K + k0 + sk + 8];
        __syncthreads();
        *(uint4*)&As[srow][sk] = ga0;
        *(uint4*)&As[srow][sk + 8] = ga1;
        *(uint4*)&Bs[srow][sk] = gb0;
        *(uint4*)&Bs[srow][sk + 8] = gb1;
        __syncthreads();
        short8 af[4], bfr[4];
#pragma unroll
        for (int mf = 0; mf < 4; ++mf)
            af[mf] = *(const short8*)&As[wm * 64 + mf * 16 + fr][kb];
#pragma unroll
        for (int nf = 0; nf < 4; ++nf)
            bfr[nf] = *(const short8*)&Bs[wn * 64 + nf * 16 + fr][kb];
#pragma unroll
        for (int mf = 0; mf < 4; ++mf)
#pragma unroll
            for (int nf = 0; nf < 4; ++nf)
                acc[mf][nf] = __builtin_amdgcn_mfma_f32_16x16x32_bf16(
                    af[mf], bfr[nf], acc[mf][nf], 0, 0, 0);
    }
    const int fq = lane >> 4;
#pragma unroll
    for (int nf = 0; nf < 4; ++nf) {
        const long col = col0 + wn * 64 + nf * 16 + fr;
        const float bv = bias[col];
#pragma unroll
        for (int mf = 0; mf < 4; ++mf) {
#pragma unroll
            for (int i = 0; i < 4; ++i) {
                const long r = row0 + wm * 64 + mf * 16 + fq * 4 + i;
                float vv = acc[mf][nf][i] + bv;
                if (RELU) vv = fmaxf(vv, 0.f);
                if (OUTBF) ((unsigned short*)Cv)[r * ldc + col] = f2b(vv);
                else       ((float*)Cv)[r * ldc + col] = vv;
            }
        }
    }
}

// =====================================================================
// Conv stage (chunk of GC graphs, g0 = first graph).
// =====================================================================
__global__ void init_md(unsigned* __restrict__ m_ord, float* __restrict__ denom) {
    int gid = blockIdx.x * blockDim.x + threadIdx.x;
    if (gid < CONV_ROWS * HH) { m_ord[gid] = 0u; denom[gid] = 0.f; }
}

__global__ __launch_bounds__(256) void conv_alpha(
    const unsigned short* __restrict__ qb, const unsigned short* __restrict__ kb,
    const int* __restrict__ eidx, const float* __restrict__ eattr,
    const float* __restrict__ W_edge, const float* __restrict__ b_edge,
    float* __restrict__ alpha, unsigned* __restrict__ m_ord, int g0)
{
    __shared__ float We[6 * 256];
    __shared__ float Be[256];
    const int tid = threadIdx.x;
    for (int i = tid; i < 6 * 256; i += 256) We[i] = W_edge[i];
    Be[tid] = b_edge[tid];
    __syncthreads();
    const int wave = tid >> 6, lane = tid & 63;
    long el = (long)blockIdx.x * 4 + wave;
    int gl = (int)(el / EE), e = (int)(el % EE);
    int g = g0 + gl;
    int src = eidx[((long)g * 2 + 0) * EE + e];
    int tgt = eidx[((long)g * 2 + 1) * EE + e];
    long sf = (long)gl * NN + src;
    long tf = (long)gl * NN + tgt;
    long ge = (long)g * EE + e;
    float ea[6];
#pragma unroll
    for (int j = 0; j < 6; ++j) ea[j] = eattr[ge * 6 + j];
    const float scale = 0.17677669529663687f;  // 1/sqrt(32)
#pragma unroll
    for (int i = 0; i < 4; ++i) {
        int d = lane + 64 * i;
        float ef = Be[d];
#pragma unroll
        for (int j = 0; j < 6; ++j) ef += ea[j] * We[j * 256 + d];
        float p = b2f(qb[tf * 256 + d]) * (b2f(kb[sf * 256 + d]) + ef);
#pragma unroll
        for (int m = 16; m >= 1; m >>= 1) p += __shfl_xor(p, m, 64);
        if ((lane & 31) == 0) {
            int h = d >> 5;
            float a = p * scale;
            alpha[el * 8 + h] = a;
            atomicMax(&m_ord[tf * 8 + h], f2ord(a));
        }
    }
}

__global__ void conv_exp(
    const int* __restrict__ eidx, float* __restrict__ alpha,
    const unsigned* __restrict__ m_ord, float* __restrict__ denom, int g0)
{
    long gid = (long)blockIdx.x * blockDim.x + threadIdx.x;
    if (gid >= (long)CONV_EDGES * 8) return;
    long el = gid >> 3;
    int h = (int)(gid & 7);
    int gl = (int)(el / EE), e = (int)(el % EE);
    int tgt = eidx[((long)(g0 + gl) * 2 + 1) * EE + e];
    long tf = (long)gl * NN + tgt;
    float m = ord2f(m_ord[tf * 8 + h]);
    float a = expf(alpha[gid] - m);
    alpha[gid] = a;
    atomicAdd(&denom[tf * 8 + h], a);
}

__global__ __launch_bounds__(256) void conv_agg(
    const unsigned short* __restrict__ vb,
    const int* __restrict__ eidx, const float* __restrict__ eattr,
    const float* __restrict__ W_edge, const float* __restrict__ b_edge,
    const float* __restrict__ alpha, const float* __restrict__ denom,
    float* __restrict__ out, int g0)
{
    __shared__ float We[6 * 256];
    __shared__ float Be[256];
    const int tid = threadIdx.x;
    for (int i = tid; i < 6 * 256; i += 256) We[i] = W_edge[i];
    Be[tid] = b_edge[tid];
    __syncthreads();
    const int wave = tid >> 6, lane = tid & 63;
    long el = (long)blockIdx.x * 4 + wave;
    int gl = (int)(el / EE), e = (int)(el % EE);
    int g = g0 + gl;
    int src = eidx[((long)g * 2 + 0) * EE + e];
    int tgt = eidx[((long)g * 2 + 1) * EE + e];
    long sf = (long)gl * NN + src;
    long tf = (long)gl * NN + tgt;
    long ge = (long)g * EE + e;
    float ea[6];
#pragma unroll
    for (int j = 0; j < 6; ++j) ea[j] = eattr[ge * 6 + j];
    float w[8];
#pragma unroll
    for (int h = 0; h < 8; ++h) w[h] = alpha[el * 8 + h] / denom[tf * 8 + h];
    long orow = (long)g * NN + tgt;
#pragma unroll
    for (int i = 0; i < 4; ++i) {
        int d = lane + 64 * i;
        float ef = Be[d];
#pragma unroll
        for (int j = 0; j < 6; ++j) ef += ea[j] * We[j * 256 + d];
        float val = w[d >> 5] * (b2f(vb[sf * 256 + d]) + ef);
        atomicAdd(&out[orow * 256 + d], val);
    }
}

// conv result fp32 [b*T+t][n][256] -> seq bf16 [t*BN + b*N + n][256]
__global__ void transpose_bt(const float* __restrict__ in, unsigned short* __restrict__ out) {
    long gid = (long)blockIdx.x * blockDim.x + threadIdx.x;  // NM*64 float4s
    long row = gid >> 6;
    int c4 = (int)(gid & 63);
    int n = (int)(row % NN);
    int bt = (int)(row / NN);
    int t = bt % TT, b = bt / TT;
    long orow = (long)t * BN + (long)b * NN + n;
    float4 v = ((const float4*)in)[row * 64 + c4];
    ushort4 o;
    o.x = f2b(v.x); o.y = f2b(v.y); o.z = f2b(v.z); o.w = f2b(v.w);
    ((ushort4*)out)[orow * 64 + c4] = o;
}

// temporal attention over T=5 (bf16 q/k/v; o written in-place over q).
// One 32-lane group per (bn, head); each group owns its q-slice exclusively.
__global__ __launch_bounds__(256) void mha_time(
    unsigned short* __restrict__ q, const unsigned short* __restrict__ k,
    const unsigned short* __restrict__ v)
{
    const int tid = threadIdx.x;
    const int grp = tid >> 5, c = tid & 31;
    long pair = (long)blockIdx.x * 8 + grp;   // BN*HH pairs
    int h = (int)(pair & 7);
    long bn = pair >> 3;
    const float scale = 0.17677669529663687f;
    float qv[TT], kv[TT], vv[TT];
    long r[TT];
#pragma unroll
    for (int t = 0; t < TT; ++t) {
        r[t] = ((long)t * BN + bn) * 256 + h * 32 + c;
        qv[t] = b2f(q[r[t]]); kv[t] = b2f(k[r[t]]); vv[t] = b2f(v[r[t]]);
    }
    float s[TT][TT];
#pragma unroll
    for (int t = 0; t < TT; ++t)
#pragma unroll
        for (int u = 0; u < TT; ++u) {
            float p = qv[t] * kv[u];
#pragma unroll
            for (int m = 16; m >= 1; m >>= 1) p += __shfl_xor(p, m, 64);
            s[t][u] = p * scale;
        }
#pragma unroll
    for (int t = 0; t < TT; ++t) {
        float mx = s[t][0];
#pragma unroll
        for (int u = 1; u < TT; ++u) mx = fmaxf(mx, s[t][u]);
        float sm = 0.f;
#pragma unroll
        for (int u = 0; u < TT; ++u) { s[t][u] = expf(s[t][u] - mx); sm += s[t][u]; }
        float inv = 1.f / sm;
        float o = 0.f;
#pragma unroll
        for (int u = 0; u < TT; ++u) o += s[t][u] * vv[u];
        q[r[t]] = f2b(o * inv);
    }
}

// seq(bf16) = LayerNorm(seq + res(fp32)) * g + b; one wave per row, 4 rows/block
__global__ __launch_bounds__(256) void ln_residual(
    unsigned short* __restrict__ seq, const float* __restrict__ res,
    const float* __restrict__ g, const float* __restrict__ b)
{
    const int wave = threadIdx.x >> 6, lane = threadIdx.x & 63;
    long row = (long)blockIdx.x * 4 + wave;
    const ushort4 s4 = *(const ushort4*)&seq[row * 256 + lane * 4];
    const float4 r4 = *(const float4*)&res[row * 256 + lane * 4];
    float x[4] = { b2f(s4.x) + r4.x, b2f(s4.y) + r4.y, b2f(s4.z) + r4.z, b2f(s4.w) + r4.w };
    float sum = x[0] + x[1] + x[2] + x[3];
#pragma unroll
    for (int m = 32; m >= 1; m >>= 1) sum += __shfl_xor(sum, m, 64);
    float mean = sum * (1.f / 256.f);
    float vs = 0.f;
#pragma unroll
    for (int i = 0; i < 4; ++i) { float dl = x[i] - mean; vs += dl * dl; }
#pragma unroll
    for (int m = 32; m >= 1; m >>= 1) vs += __shfl_xor(vs, m, 64);
    float inv = rsqrtf(vs * (1.f / 256.f) + 1e-5f);
    ushort4 o;
    float* gp = (float*)g;
    o.x = f2b((x[0] - mean) * inv * gp[lane * 4 + 0] + b[lane * 4 + 0]);
    o.y = f2b((x[1] - mean) * inv * gp[lane * 4 + 1] + b[lane * 4 + 1]);
    o.z = f2b((x[2] - mean) * inv * gp[lane * 4 + 2] + b[lane * 4 + 2]);
    o.w = f2b((x[3] - mean) * inv * gp[lane * 4 + 3] + b[lane * 4 + 3]);
    *(ushort4*)&seq[row * 256 + lane * 4] = o;
}

// out[row][0..9] = seq[t=T-1 rows](bf16) @ W_out + b_out ; one block per row
__global__ __launch_bounds__(256) void final_out(
    const unsigned short* __restrict__ seq, const float* __restrict__ Wd,
    const float* __restrict__ bd, float* __restrict__ out)
{
    __shared__ float xs[256];
    long row = blockIdx.x;
    xs[threadIdx.x] = b2f(seq[((long)(TT - 1) * BN + row) * 256 + threadIdx.x]);
    __syncthreads();
    const int wv = threadIdx.x >> 6, lane = threadIdx.x & 63;
    for (int o = wv; o < NCLS; o += 4) {
        float p = 0.f;
#pragma unroll
        for (int i = 0; i < 4; ++i) {
            int kk = lane + 64 * i;
            p += xs[kk] * Wd[kk * NCLS + o];
        }
#pragma unroll
        for (int m = 32; m >= 1; m >>= 1) p += __shfl_xor(p, m, 64);
        if (lane == 0) out[row * NCLS + o] = p + bd[o];
    }
}

__global__ void fill_sentinel(float* __restrict__ out, int n) {
    int gid = blockIdx.x * blockDim.x + threadIdx.x;
    if (gid < n) out[gid] = 1.0e6f;
}

// =====================================================================
extern "C" void kernel_launch(void* const* d_in, const int* in_sizes, int n_in,
                              void* d_out, int out_size, void* d_ws, size_t ws_size,
                              hipStream_t stream) {
    const float* xseq  = (const float*)d_in[0];
    const int*   eidx  = (const int*)d_in[1];
    const float* eattr = (const float*)d_in[2];
    const float* W_node = (const float*)d_in[3];
    const float* b_node = (const float*)d_in[4];
    const float* W_edge = (const float*)d_in[5];
    const float* b_edge = (const float*)d_in[6];
    const float* Wq = (const float*)d_in[7];  const float* bq = (const float*)d_in[8];
    const float* Wk = (const float*)d_in[9];  const float* bk = (const float*)d_in[10];
    const float* Wv = (const float*)d_in[11]; const float* bv = (const float*)d_in[12];
    const float* Ws = (const float*)d_in[13]; const float* bs = (const float*)d_in[14];
    const float* Wqkv = (const float*)d_in[15]; const float* bqkv = (const float*)d_in[16];
    const float* Wo = (const float*)d_in[17];   const float* bo = (const float*)d_in[18];
    const float* W1 = (const float*)d_in[19];   const float* b1 = (const float*)d_in[20];
    const float* W2 = (const float*)d_in[21];   const float* b2 = (const float*)d_in[22];
    const float* g_ln1 = (const float*)d_in[23]; const float* b_ln1 = (const float*)d_in[24];
    const float* g_ln2 = (const float*)d_in[25]; const float* b_ln2 = (const float*)d_in[26];
    const float* W_out = (const float*)d_in[27]; const float* b_out = (const float*)d_in[28];
    float* out = (float*)d_out;

    // ---- workspace layout ----
    const long SZ = (long)NM * DD;            // 20,971,520 elements
    unsigned short* Abf = (unsigned short*)d_ws;     // seq activations bf16 (40MB)
    unsigned short* Zu  = Abf + SZ;                  // Z region: 3*SZ ushorts (120MB)
    // stage 1 views of Z:
    float* R32 = (float*)Zu;                         // conv fp32 accum (80MB)
    unsigned short* Sq_ = Zu + 2 * SZ;               // conv chunk scratch
    unsigned short* Sk_ = Sq_ + (long)CONV_ROWS * DD;
    unsigned short* Sv_ = Sk_ + (long)CONV_ROWS * DD;
    float* al = (float*)(Sv_ + (long)CONV_ROWS * DD);    // CONV_EDGES*8 fp32
    unsigned* mo = (unsigned*)(al + (long)CONV_EDGES * 8);
    float* dn = (float*)(mo + CONV_ROWS * 8);
    // stage 2 views of Z:
    unsigned short* Zq = Zu;                 // q, then attn-out (in-place)
    unsigned short* Zk = Zu + SZ;
    unsigned short* Zv = Zu + 2 * SZ;
    float* res32 = (float*)(Zu + SZ);        // Wo-out residual fp32 (80MB, over K+V)
    unsigned short* Hid = Zu + SZ;           // FFN hidden bf16 [MR][2048] (64MB)
    float* res32f = (float*)(Zu + SZ + 33554432);   // FFN residual fp32 [MR][256] (16MB)
    // weights region after Z:
    unsigned short* WX = Zu + 3 * SZ;
    unsigned short* xbf = WX;                             // 81920*64
    unsigned short* wtN = xbf + (long)NM * FIN;           // [256][64]
    unsigned short* wtQ = wtN + 256 * 64;
    unsigned short* wtK = wtQ + 65536;
    unsigned short* wtV = wtK + 65536;
    unsigned short* wtS = wtV + 65536;
    unsigned short* wtQKV = wtS + 65536;                  // 3 * [768][256]
    unsigned short* wtO = wtQKV + 3L * 768 * 256;         // 3 * [256][256]
    unsigned short* wtW1 = wtO + 3L * 65536;              // 3 * [2048][256]
    unsigned short* wtW2 = wtW1 + 3L * 2048 * 256;        // 3 * [256][2048]
    unsigned short* wend = wtW2 + 3L * 256 * 2048;
    const size_t need = (size_t)((char*)wend - (char*)d_ws);
    if (ws_size < need) {
        fill_sentinel<<<dim3((out_size + 255) / 256), dim3(256), 0, stream>>>(out, out_size);
        return;
    }

    dim3 blk(256);
    dim3 tb(32, 8);

    // ---- prologue: convert weights (fp32 [K][N] -> bf16 [N][K]) and x ----
    xconvert<<<dim3((unsigned)((long)NM * FIN / 4 / 256)), blk, 0, stream>>>(xseq, xbf, (long)NM * FIN / 4);
    wtrans<<<dim3(DD / 32, FIN / 32), tb, 0, stream>>>(W_node, wtN, FIN, DD);
    wtrans<<<dim3(DD / 32, DD / 32), tb, 0, stream>>>(Wq, wtQ, DD, DD);
    wtrans<<<dim3(DD / 32, DD / 32), tb, 0, stream>>>(Wk, wtK, DD, DD);
    wtrans<<<dim3(DD / 32, DD / 32), tb, 0, stream>>>(Wv, wtV, DD, DD);
    wtrans<<<dim3(DD / 32, DD / 32), tb, 0, stream>>>(Ws, wtS, DD, DD);
    for (int l = 0; l < 3; ++l) {
        wtrans<<<dim3(768 / 32, DD / 32), tb, 0, stream>>>(Wqkv + (long)l * DD * 768, wtQKV + (long)l * 768 * 256, DD, 768);
        wtrans<<<dim3(DD / 32, DD / 32), tb, 0, stream>>>(Wo + (long)l * DD * DD, wtO + (long)l * 65536, DD, DD);
        wtrans<<<dim3(FFD / 32, DD / 32), tb, 0, stream>>>(W1 + (long)l * DD * FFD, wtW1 + (long)l * 2048 * 256, DD, FFD);
        wtrans<<<dim3(DD / 32, FFD / 32), tb, 0, stream>>>(W2 + (long)l * FFD * DD, wtW2 + (long)l * 256 * 2048, FFD, DD);
    }

    // ---- stage 1: node embed (Abf = h), skip (R32 = h@Ws+bs), conv chunks ----
    gemm_mfma<false, true><<<dim3(NM / 128, DD / 128), blk, 0, stream>>>(
        xbf, FIN, wtN, b_node, Abf, DD, FIN);
    gemm_mfma<false, false><<<dim3(NM / 128, DD / 128), blk, 0, stream>>>(
        Abf, DD, wtS, bs, R32, DD, DD);

    for (int gc = 0; gc < GG / GC; ++gc) {
        const int g0 = gc * GC;
        const long row0 = (long)g0 * NN;
        gemm_mfma<false, true><<<dim3(CONV_ROWS / 128, DD / 128), blk, 0, stream>>>(
            Abf + row0 * DD, DD, wtQ, bq, Sq_, DD, DD);
        gemm_mfma<false, true><<<dim3(CONV_ROWS / 128, DD / 128), blk, 0, stream>>>(
            Abf + row0 * DD, DD, wtK, bk, Sk_, DD, DD);
        gemm_mfma<false, true><<<dim3(CONV_ROWS / 128, DD / 128), blk, 0, stream>>>(
            Abf + row0 * DD, DD, wtV, bv, Sv_, DD, DD);
        init_md<<<dim3(CONV_ROWS * HH / 256), blk, 0, stream>>>(mo, dn);
        conv_alpha<<<dim3(CONV_EDGES / 4), blk, 0, stream>>>(
            Sq_, Sk_, eidx, eattr, W_edge, b_edge, al, mo, g0);
        conv_exp<<<dim3(CONV_EDGES * 8 / 256), blk, 0, stream>>>(eidx, al, mo, dn, g0);
        conv_agg<<<dim3(CONV_EDGES / 4), blk, 0, stream>>>(
            Sv_, eidx, eattr, W_edge, b_edge, al, dn, R32, g0);
    }

    // ---- reshape to [T, B*N, D]: R32 -> Abf (bf16) ----
    transpose_bt<<<dim3(NM * 64 / 256), blk, 0, stream>>>(R32, Abf);

    // ---- stage 2: 3 temporal transformer encoder layers ----
    for (int l = 0; l < 3; ++l) {
        const unsigned short* wql = wtQKV + (long)l * 768 * 256;
        const float* bl = bqkv + (long)l * 768;
        gemm_mfma<false, true><<<dim3(NM / 128, DD / 128), blk, 0, stream>>>(
            Abf, DD, wql + 0 * 256 * 256, bl + 0, Zq, DD, DD);
        gemm_mfma<false, true><<<dim3(NM / 128, DD / 128), blk, 0, stream>>>(
            Abf, DD, wql + 1L * 256 * 256, bl + 256, Zk, DD, DD);
        gemm_mfma<false, true><<<dim3(NM / 128, DD / 128), blk, 0, stream>>>(
            Abf, DD, wql + 2L * 256 * 256, bl + 512, Zv, DD, DD);
        mha_time<<<dim3(BN * HH / 8), blk, 0, stream>>>(Zq, Zk, Zv);
        gemm_mfma<false, false><<<dim3(NM / 128, DD / 128), blk, 0, stream>>>(
            Zq, DD, wtO + (long)l * 65536, bo + (long)l * DD, res32, DD, DD);
        ln_residual<<<dim3(NM / 4), blk, 0, stream>>>(Abf, res32, g_ln1 + l * DD, b_ln1 + l * DD);
        for (int mr = 0; mr < NM / MR; ++mr) {
            const long r0 = (long)mr * MR;
            gemm_mfma<true, true><<<dim3(MR / 128, FFD / 128), blk, 0, stream>>>(
                Abf + r0 * DD, DD, wtW1 + (long)l * 2048 * 256, b1 + (long)l * FFD, Hid, FFD, DD);
            gemm_mfma<false, false><<<dim3(MR / 128, DD / 128), blk, 0, stream>>>(
                Hid, FFD, wtW2 + (long)l * 256 * 2048, b2 + (long)l * DD, res32f, DD, FFD);
            ln_residual<<<dim3(MR / 4), blk, 0, stream>>>(
                Abf + r0 * DD, res32f, g_ln2 + l * DD, b_ln2 + l * DD);
        }
    }

    // ---- output head ----
    final_out<<<dim3(BN), blk, 0, stream>>>(Abf, W_out, b_out, out);
}

// Round 4
// 2945.622 us; speedup vs baseline: 7.5069x; 1.6392x over previous
//
#include <hip/hip_runtime.h>
#include <math.h>

// ---- problem constants ----
#define BB   8
#define TT   5
#define NN   2048
#define FIN  64
#define EE   32768
#define DD   256
#define HH   8
#define FFD  2048
#define NCLS 10
#define GG   (BB*TT)        // 40 graphs
#define BN   (BB*NN)        // 16384
#define NM   (GG*NN)        // 81920 rows (= TT*BN)
#define NE   ((long)GG*EE)  // 1310720 edges

#define MR        16384           // rows per FFN chunk (5 chunks)

typedef __attribute__((ext_vector_type(8))) short short8;
typedef __attribute__((ext_vector_type(4))) float f32x4;

// ---- bf16 helpers (RNE) ----
__device__ __forceinline__ unsigned short f2b(float f) {
    unsigned u = __float_as_uint(f);
    u = (u + 0x7fffu + ((u >> 16) & 1u)) >> 16;
    return (unsigned short)u;
}
__device__ __forceinline__ float b2f(unsigned short b) {
    return __uint_as_float(((unsigned)b) << 16);
}

// =====================================================================
// Weight transpose+convert: in fp32 [K][N] row-major -> out bf16 [N][K]
// =====================================================================
__global__ void wtrans(const float* __restrict__ in, unsigned short* __restrict__ out,
                       int K, int N) {
    __shared__ float t[32][33];
    const int n0 = blockIdx.x * 32, k0 = blockIdx.y * 32;
    const int tx = threadIdx.x, ty = threadIdx.y;
    for (int i = ty; i < 32; i += 8) t[i][tx] = in[(long)(k0 + i) * N + n0 + tx];
    __syncthreads();
    for (int i = ty; i < 32; i += 8)
        out[(long)(n0 + i) * K + k0 + tx] = f2b(t[tx][i]);
}

// fp32 -> bf16 elementwise (n4 float4 groups)
__global__ void xconvert(const float* __restrict__ in, unsigned short* __restrict__ out, long n4) {
    long gid = (long)blockIdx.x * blockDim.x + threadIdx.x;
    if (gid >= n4) return;
    float4 v = ((const float4*)in)[gid];
    ushort4 o;
    o.x = f2b(v.x); o.y = f2b(v.y); o.z = f2b(v.z); o.w = f2b(v.w);
    ((ushort4*)out)[gid] = o;
}

// =====================================================================
// bf16 MFMA GEMM: C[M x N] = A[M x K] @ W[K x N] + bias
// A bf16 row-major (lda), WT = W^T bf16 [N][K], C fp32 or bf16 (ldc).
// 128x128 tile, BK=32, 256 threads = 4 waves (2x2), 16x16x32 MFMA.
// =====================================================================
template <bool RELU, bool OUTBF>
__global__ __launch_bounds__(256) void gemm_mfma(
    const unsigned short* __restrict__ A, int lda,
    const unsigned short* __restrict__ WT,
    const float* __restrict__ bias,
    void* __restrict__ Cv, int ldc, int K)
{
    __shared__ unsigned short As[128][40];
    __shared__ unsigned short Bs[128][40];
    const int tid = threadIdx.x;
    const int wid = tid >> 6, lane = tid & 63;
    const int wm = wid >> 1, wn = wid & 1;
    const long row0 = (long)blockIdx.x * 128;
    const long col0 = (long)blockIdx.y * 128;
    const int srow = tid >> 1;
    const int sk = (tid & 1) * 16;
    f32x4 acc[4][4] = {};
    const int kb = (lane >> 4) * 8;
    const int fr = lane & 15;
    for (int k0 = 0; k0 < K; k0 += 32) {
        const uint4 ga0 = *(const uint4*)&A[(row0 + srow) * lda + k0 + sk];
        const uint4 ga1 = *(const uint4*)&A[(row0 + srow) * lda + k0 + sk + 8];
        const uint4 gb0 = *(const uint4*)&WT[(col0 + srow) * (long)K + k0 + sk];
        const uint4 gb1 = *(const uint4*)&WT[(col0 + srow) * (long)K + k0 + sk + 8];
        __syncthreads();
        *(uint4*)&As[srow][sk] = ga0;
        *(uint4*)&As[srow][sk + 8] = ga1;
        *(uint4*)&Bs[srow][sk] = gb0;
        *(uint4*)&Bs[srow][sk + 8] = gb1;
        __syncthreads();
        short8 af[4], bfr[4];
#pragma unroll
        for (int mf = 0; mf < 4; ++mf)
            af[mf] = *(const short8*)&As[wm * 64 + mf * 16 + fr][kb];
#pragma unroll
        for (int nf = 0; nf < 4; ++nf)
            bfr[nf] = *(const short8*)&Bs[wn * 64 + nf * 16 + fr][kb];
#pragma unroll
        for (int mf = 0; mf < 4; ++mf)
#pragma unroll
            for (int nf = 0; nf < 4; ++nf)
                acc[mf][nf] = __builtin_amdgcn_mfma_f32_16x16x32_bf16(
                    af[mf], bfr[nf], acc[mf][nf], 0, 0, 0);
    }
    const int fq = lane >> 4;
#pragma unroll
    for (int nf = 0; nf < 4; ++nf) {
        const long col = col0 + wn * 64 + nf * 16 + fr;
        const float bv = bias[col];
#pragma unroll
        for (int mf = 0; mf < 4; ++mf) {
#pragma unroll
            for (int i = 0; i < 4; ++i) {
                const long r = row0 + wm * 64 + mf * 16 + fq * 4 + i;
                float vv = acc[mf][nf][i] + bv;
                if (RELU) vv = fmaxf(vv, 0.f);
                if (OUTBF) ((unsigned short*)Cv)[r * ldc + col] = f2b(vv);
                else       ((float*)Cv)[r * ldc + col] = vv;
            }
        }
    }
}

// =====================================================================
// CSR build: edges grouped by global target row tf = g*NN + tgt
// =====================================================================
__global__ void csr_init(int* __restrict__ cnt, int* __restrict__ fill) {
    int gid = blockIdx.x * blockDim.x + threadIdx.x;
    if (gid < NM) { cnt[gid] = 0; fill[gid] = 0; }
}

__global__ void csr_count(const int* __restrict__ eidx, int* __restrict__ cnt) {
    long el = (long)blockIdx.x * blockDim.x + threadIdx.x;
    if (el >= NE) return;
    int g = (int)(el >> 15), e = (int)(el & (EE - 1));
    int tgt = eidx[((long)g * 2 + 1) * EE + e];
    atomicAdd(&cnt[g * NN + tgt], 1);
}

// single-block exclusive scan over NM counts (1024 threads x 80 each)
__global__ __launch_bounds__(1024) void csr_scan(const int* __restrict__ cnt, int* __restrict__ off) {
    __shared__ int part[1024];
    const int t = threadIdx.x;
    const int base = t * (NM / 1024);
    int s = 0;
    for (int i = 0; i < NM / 1024; ++i) s += cnt[base + i];
    part[t] = s;
    __syncthreads();
    for (int d = 1; d < 1024; d <<= 1) {
        int v = (t >= d) ? part[t - d] : 0;
        __syncthreads();
        part[t] += v;
        __syncthreads();
    }
    int run = (t == 0) ? 0 : part[t - 1];
    for (int i = 0; i < NM / 1024; ++i) { off[base + i] = run; run += cnt[base + i]; }
    if (t == 1023) off[NM] = run;
}

__global__ void csr_scatter(const int* __restrict__ eidx, const int* __restrict__ off,
                            int* __restrict__ fill, int* __restrict__ csr) {
    long el = (long)blockIdx.x * blockDim.x + threadIdx.x;
    if (el >= NE) return;
    int g = (int)(el >> 15), e = (int)(el & (EE - 1));
    int tgt = eidx[((long)g * 2 + 1) * EE + e];
    int tf = g * NN + tgt;
    int pos = atomicAdd(&fill[tf], 1);
    csr[off[tf] + pos] = (int)el;
}

// =====================================================================
// Fused TransformerConv: one 64-lane wave per target node. Gathers k/v of
// incident edges via CSR, edge-embedding on the fly, 8-head dot via 8-lane
// shuffle reduce, online softmax, registers-only accumulation.
// Writes conv output (bf16) OVER the q buffer (each wave owns its row).
// =====================================================================
__global__ __launch_bounds__(256) void conv_fused(
    unsigned short* __restrict__ q, const unsigned short* __restrict__ k,
    const unsigned short* __restrict__ v,
    const int* __restrict__ eidx, const float* __restrict__ eattr,
    const float* __restrict__ W_edge, const float* __restrict__ b_edge,
    const int* __restrict__ off, const int* __restrict__ csr)
{
    __shared__ float We[6 * 256];
    __shared__ float Be[256];
    const int tid = threadIdx.x;
    for (int i = tid; i < 6 * 256; i += 256) We[i] = W_edge[i];
    Be[tid] = b_edge[tid];
    __syncthreads();
    const int wave = tid >> 6, lane = tid & 63;
    const long tf = (long)blockIdx.x * 4 + wave;
    const int d0 = lane * 4;
    const ushort4 q4 = *(const ushort4*)&q[tf * 256 + d0];
    const float q0 = b2f(q4.x), q1 = b2f(q4.y), q2 = b2f(q4.z), q3 = b2f(q4.w);
    const float be0 = Be[d0], be1 = Be[d0 + 1], be2 = Be[d0 + 2], be3 = Be[d0 + 3];
    const float scale = 0.17677669529663687f;  // 1/sqrt(32)
    float m = -1e30f, s = 0.f;
    float a0 = 0.f, a1 = 0.f, a2 = 0.f, a3 = 0.f;
    const int jb = off[tf], je = off[tf + 1];
    for (int j = jb; j < je; ++j) {
        const int el = csr[j];
        const int g = el >> 15, e = el & (EE - 1);
        const int src = eidx[((long)g * 2) * EE + e];
        const long sf = (long)g * NN + src;
        const ushort4 k4 = *(const ushort4*)&k[sf * 256 + d0];
        const ushort4 v4 = *(const ushort4*)&v[sf * 256 + d0];
        float ea[6];
#pragma unroll
        for (int j2 = 0; j2 < 6; ++j2) ea[j2] = eattr[(long)el * 6 + j2];
        float ef0 = be0, ef1 = be1, ef2 = be2, ef3 = be3;
#pragma unroll
        for (int j2 = 0; j2 < 6; ++j2) {
            const float* w = &We[j2 * 256 + d0];
            ef0 += ea[j2] * w[0]; ef1 += ea[j2] * w[1];
            ef2 += ea[j2] * w[2]; ef3 += ea[j2] * w[3];
        }
        float p = q0 * (b2f(k4.x) + ef0) + q1 * (b2f(k4.y) + ef1)
                + q2 * (b2f(k4.z) + ef2) + q3 * (b2f(k4.w) + ef3);
        p += __shfl_xor(p, 1, 64);
        p += __shfl_xor(p, 2, 64);
        p += __shfl_xor(p, 4, 64);   // 8-lane group = one head (32 dims)
        const float a = p * scale;
        const float nm = fmaxf(m, a);
        const float r = __expf(m - nm);   // 1 if no new max, 0 on first edge
        const float w = __expf(a - nm);
        s = s * r + w;
        a0 = a0 * r + w * (b2f(v4.x) + ef0);
        a1 = a1 * r + w * (b2f(v4.y) + ef1);
        a2 = a2 * r + w * (b2f(v4.z) + ef2);
        a3 = a3 * r + w * (b2f(v4.w) + ef3);
        m = nm;
    }
    const float inv = (s > 0.f) ? 1.f / s : 0.f;
    ushort4 o;
    o.x = f2b(a0 * inv); o.y = f2b(a1 * inv);
    o.z = f2b(a2 * inv); o.w = f2b(a3 * inv);
    *(ushort4*)&q[tf * 256 + d0] = o;
}

// seq(bf16, [t*BN+b*N+n]) = conv(bf16, [(b*T+t)*N+n]) + skip(bf16, same layout)
__global__ void transpose_add(const unsigned short* __restrict__ conv,
                              const unsigned short* __restrict__ skip,
                              unsigned short* __restrict__ out) {
    long gid = (long)blockIdx.x * blockDim.x + threadIdx.x;  // NM*64 ushort4s
    long row = gid >> 6;
    int c4 = (int)(gid & 63);
    int n = (int)(row % NN);
    int bt = (int)(row / NN);
    int t = bt % TT, b = bt / TT;
    long orow = (long)t * BN + (long)b * NN + n;
    ushort4 cv = ((const ushort4*)conv)[row * 64 + c4];
    ushort4 sv = ((const ushort4*)skip)[row * 64 + c4];
    ushort4 o;
    o.x = f2b(b2f(cv.x) + b2f(sv.x));
    o.y = f2b(b2f(cv.y) + b2f(sv.y));
    o.z = f2b(b2f(cv.z) + b2f(sv.z));
    o.w = f2b(b2f(cv.w) + b2f(sv.w));
    ((ushort4*)out)[orow * 64 + c4] = o;
}

// temporal attention over T=5 (bf16 q/k/v; o written in-place over q).
__global__ __launch_bounds__(256) void mha_time(
    unsigned short* __restrict__ q, const unsigned short* __restrict__ k,
    const unsigned short* __restrict__ v)
{
    const int tid = threadIdx.x;
    const int grp = tid >> 5, c = tid & 31;
    long pair = (long)blockIdx.x * 8 + grp;   // BN*HH pairs
    int h = (int)(pair & 7);
    long bn = pair >> 3;
    const float scale = 0.17677669529663687f;
    float qv[TT], kv[TT], vv[TT];
    long r[TT];
#pragma unroll
    for (int t = 0; t < TT; ++t) {
        r[t] = ((long)t * BN + bn) * 256 + h * 32 + c;
        qv[t] = b2f(q[r[t]]); kv[t] = b2f(k[r[t]]); vv[t] = b2f(v[r[t]]);
    }
    float s[TT][TT];
#pragma unroll
    for (int t = 0; t < TT; ++t)
#pragma unroll
        for (int u = 0; u < TT; ++u) {
            float p = qv[t] * kv[u];
#pragma unroll
            for (int m = 16; m >= 1; m >>= 1) p += __shfl_xor(p, m, 64);
            s[t][u] = p * scale;
        }
#pragma unroll
    for (int t = 0; t < TT; ++t) {
        float mx = s[t][0];
#pragma unroll
        for (int u = 1; u < TT; ++u) mx = fmaxf(mx, s[t][u]);
        float sm = 0.f;
#pragma unroll
        for (int u = 0; u < TT; ++u) { s[t][u] = expf(s[t][u] - mx); sm += s[t][u]; }
        float inv = 1.f / sm;
        float o = 0.f;
#pragma unroll
        for (int u = 0; u < TT; ++u) o += s[t][u] * vv[u];
        q[r[t]] = f2b(o * inv);
    }
}

// seq(bf16) = LayerNorm(seq + res(fp32)) * g + b; one wave per row
__global__ __launch_bounds__(256) void ln_residual(
    unsigned short* __restrict__ seq, const float* __restrict__ res,
    const float* __restrict__ g, const float* __restrict__ b)
{
    const int wave = threadIdx.x >> 6, lane = threadIdx.x & 63;
    long row = (long)blockIdx.x * 4 + wave;
    const ushort4 s4 = *(const ushort4*)&seq[row * 256 + lane * 4];
    const float4 r4 = *(const float4*)&res[row * 256 + lane * 4];
    float x[4] = { b2f(s4.x) + r4.x, b2f(s4.y) + r4.y, b2f(s4.z) + r4.z, b2f(s4.w) + r4.w };
    float sum = x[0] + x[1] + x[2] + x[3];
#pragma unroll
    for (int m = 32; m >= 1; m >>= 1) sum += __shfl_xor(sum, m, 64);
    float mean = sum * (1.f / 256.f);
    float vs = 0.f;
#pragma unroll
    for (int i = 0; i < 4; ++i) { float dl = x[i] - mean; vs += dl * dl; }
#pragma unroll
    for (int m = 32; m >= 1; m >>= 1) vs += __shfl_xor(vs, m, 64);
    float inv = rsqrtf(vs * (1.f / 256.f) + 1e-5f);
    ushort4 o;
    float* gp = (float*)g;
    o.x = f2b((x[0] - mean) * inv * gp[lane * 4 + 0] + b[lane * 4 + 0]);
    o.y = f2b((x[1] - mean) * inv * gp[lane * 4 + 1] + b[lane * 4 + 1]);
    o.z = f2b((x[2] - mean) * inv * gp[lane * 4 + 2] + b[lane * 4 + 2]);
    o.w = f2b((x[3] - mean) * inv * gp[lane * 4 + 3] + b[lane * 4 + 3]);
    *(ushort4*)&seq[row * 256 + lane * 4] = o;
}

// out[row][0..9] = seq[t=T-1 rows](bf16) @ W_out + b_out ; one block per row
__global__ __launch_bounds__(256) void final_out(
    const unsigned short* __restrict__ seq, const float* __restrict__ Wd,
    const float* __restrict__ bd, float* __restrict__ out)
{
    __shared__ float xs[256];
    long row = blockIdx.x;
    xs[threadIdx.x] = b2f(seq[((long)(TT - 1) * BN + row) * 256 + threadIdx.x]);
    __syncthreads();
    const int wv = threadIdx.x >> 6, lane = threadIdx.x & 63;
    for (int o = wv; o < NCLS; o += 4) {
        float p = 0.f;
#pragma unroll
        for (int i = 0; i < 4; ++i) {
            int kk = lane + 64 * i;
            p += xs[kk] * Wd[kk * NCLS + o];
        }
#pragma unroll
        for (int m = 32; m >= 1; m >>= 1) p += __shfl_xor(p, m, 64);
        if (lane == 0) out[row * NCLS + o] = p + bd[o];
    }
}

__global__ void fill_sentinel(float* __restrict__ out, int n) {
    int gid = blockIdx.x * blockDim.x + threadIdx.x;
    if (gid < n) out[gid] = 1.0e6f;
}

// =====================================================================
extern "C" void kernel_launch(void* const* d_in, const int* in_sizes, int n_in,
                              void* d_out, int out_size, void* d_ws, size_t ws_size,
                              hipStream_t stream) {
    const float* xseq  = (const float*)d_in[0];
    const int*   eidx  = (const int*)d_in[1];
    const float* eattr = (const float*)d_in[2];
    const float* W_node = (const float*)d_in[3];
    const float* b_node = (const float*)d_in[4];
    const float* W_edge = (const float*)d_in[5];
    const float* b_edge = (const float*)d_in[6];
    const float* Wq = (const float*)d_in[7];  const float* bq = (const float*)d_in[8];
    const float* Wk = (const float*)d_in[9];  const float* bk = (const float*)d_in[10];
    const float* Wv = (const float*)d_in[11]; const float* bv = (const float*)d_in[12];
    const float* Ws = (const float*)d_in[13]; const float* bs = (const float*)d_in[14];
    const float* Wqkv = (const float*)d_in[15]; const float* bqkv = (const float*)d_in[16];
    const float* Wo = (const float*)d_in[17];   const float* bo = (const float*)d_in[18];
    const float* W1 = (const float*)d_in[19];   const float* b1 = (const float*)d_in[20];
    const float* W2 = (const float*)d_in[21];   const float* b2 = (const float*)d_in[22];
    const float* g_ln1 = (const float*)d_in[23]; const float* b_ln1 = (const float*)d_in[24];
    const float* g_ln2 = (const float*)d_in[25]; const float* b_ln2 = (const float*)d_in[26];
    const float* W_out = (const float*)d_in[27]; const float* b_out = (const float*)d_in[28];
    float* out = (float*)d_out;

    // ---- workspace layout ----
    const long SZ = (long)NM * DD;            // 20,971,520 elements
    unsigned short* Abf = (unsigned short*)d_ws;     // seq activations bf16 (40MB)
    unsigned short* Zu  = Abf + SZ;                  // Z region: 3*SZ ushorts (120MB)
    unsigned short* Zq = Zu;                 // q -> conv out (in-place)
    unsigned short* Zk = Zu + SZ;            // k -> skip
    unsigned short* Zv = Zu + 2 * SZ;        // v
    float* res32 = (float*)(Zu + SZ);        // Wo-out residual fp32 (80MB, over K+V)
    unsigned short* Hid = Zu + SZ;           // FFN hidden bf16 [MR][2048] (64MB)
    float* res32f = (float*)(Zu + SZ + 33554432);   // FFN residual fp32 [MR][256] (16MB)
    // weights region after Z:
    unsigned short* WX = Zu + 3 * SZ;
    unsigned short* xbf = WX;                             // 81920*64
    unsigned short* wtN = xbf + (long)NM * FIN;           // [256][64]
    unsigned short* wtQ = wtN + 256 * 64;
    unsigned short* wtK = wtQ + 65536;
    unsigned short* wtV = wtK + 65536;
    unsigned short* wtS = wtV + 65536;
    unsigned short* wtQKV = wtS + 65536;                  // 3 * [768][256]
    unsigned short* wtO = wtQKV + 3L * 768 * 256;         // 3 * [256][256]
    unsigned short* wtW1 = wtO + 3L * 65536;              // 3 * [2048][256]
    unsigned short* wtW2 = wtW1 + 3L * 2048 * 256;        // 3 * [256][2048]
    // CSR region
    int* cnt  = (int*)(wtW2 + 3L * 256 * 2048);
    int* coff = cnt + NM;                                 // NM+1
    int* cfil = coff + NM + 1;
    int* csr  = cfil + NM;                                // NE ints
    char* wend = (char*)(csr + NE);
    const size_t need = (size_t)(wend - (char*)d_ws);
    if (ws_size < need) {
        fill_sentinel<<<dim3((out_size + 255) / 256), dim3(256), 0, stream>>>(out, out_size);
        return;
    }

    dim3 blk(256);
    dim3 tb(32, 8);

    // ---- prologue: convert weights (fp32 [K][N] -> bf16 [N][K]) and x ----
    xconvert<<<dim3((unsigned)((long)NM * FIN / 4 / 256)), blk, 0, stream>>>(xseq, xbf, (long)NM * FIN / 4);
    wtrans<<<dim3(DD / 32, FIN / 32), tb, 0, stream>>>(W_node, wtN, FIN, DD);
    wtrans<<<dim3(DD / 32, DD / 32), tb, 0, stream>>>(Wq, wtQ, DD, DD);
    wtrans<<<dim3(DD / 32, DD / 32), tb, 0, stream>>>(Wk, wtK, DD, DD);
    wtrans<<<dim3(DD / 32, DD / 32), tb, 0, stream>>>(Wv, wtV, DD, DD);
    wtrans<<<dim3(DD / 32, DD / 32), tb, 0, stream>>>(Ws, wtS, DD, DD);
    for (int l = 0; l < 3; ++l) {
        wtrans<<<dim3(768 / 32, DD / 32), tb, 0, stream>>>(Wqkv + (long)l * DD * 768, wtQKV + (long)l * 768 * 256, DD, 768);
        wtrans<<<dim3(DD / 32, DD / 32), tb, 0, stream>>>(Wo + (long)l * DD * DD, wtO + (long)l * 65536, DD, DD);
        wtrans<<<dim3(FFD / 32, DD / 32), tb, 0, stream>>>(W1 + (long)l * DD * FFD, wtW1 + (long)l * 2048 * 256, DD, FFD);
        wtrans<<<dim3(DD / 32, FFD / 32), tb, 0, stream>>>(W2 + (long)l * FFD * DD, wtW2 + (long)l * 256 * 2048, FFD, DD);
    }

    // ---- CSR build (independent of GEMMs) ----
    csr_init<<<dim3((NM + 255) / 256), blk, 0, stream>>>(cnt, cfil);
    csr_count<<<dim3((unsigned)(NE / 256)), blk, 0, stream>>>(eidx, cnt);
    csr_scan<<<dim3(1), dim3(1024), 0, stream>>>(cnt, coff);
    csr_scatter<<<dim3((unsigned)(NE / 256)), blk, 0, stream>>>(eidx, coff, cfil, csr);

    // ---- stage 1: h, q/k/v, fused conv, skip, transpose+add ----
    gemm_mfma<false, true><<<dim3(NM / 128, DD / 128), blk, 0, stream>>>(
        xbf, FIN, wtN, b_node, Abf, DD, FIN);
    gemm_mfma<false, true><<<dim3(NM / 128, DD / 128), blk, 0, stream>>>(
        Abf, DD, wtQ, bq, Zq, DD, DD);
    gemm_mfma<false, true><<<dim3(NM / 128, DD / 128), blk, 0, stream>>>(
        Abf, DD, wtK, bk, Zk, DD, DD);
    gemm_mfma<false, true><<<dim3(NM / 128, DD / 128), blk, 0, stream>>>(
        Abf, DD, wtV, bv, Zv, DD, DD);
    conv_fused<<<dim3(NM / 4), blk, 0, stream>>>(
        Zq, Zk, Zv, eidx, eattr, W_edge, b_edge, coff, csr);
    gemm_mfma<false, true><<<dim3(NM / 128, DD / 128), blk, 0, stream>>>(
        Abf, DD, wtS, bs, Zk, DD, DD);                  // skip over dead k
    transpose_add<<<dim3(NM * 64 / 256), blk, 0, stream>>>(Zq, Zk, Abf);

    // ---- stage 2: 3 temporal transformer encoder layers ----
    for (int l = 0; l < 3; ++l) {
        const unsigned short* wql = wtQKV + (long)l * 768 * 256;
        const float* bl = bqkv + (long)l * 768;
        gemm_mfma<false, true><<<dim3(NM / 128, DD / 128), blk, 0, stream>>>(
            Abf, DD, wql + 0 * 256 * 256, bl + 0, Zq, DD, DD);
        gemm_mfma<false, true><<<dim3(NM / 128, DD / 128), blk, 0, stream>>>(
            Abf, DD, wql + 1L * 256 * 256, bl + 256, Zk, DD, DD);
        gemm_mfma<false, true><<<dim3(NM / 128, DD / 128), blk, 0, stream>>>(
            Abf, DD, wql + 2L * 256 * 256, bl + 512, Zv, DD, DD);
        mha_time<<<dim3(BN * HH / 8), blk, 0, stream>>>(Zq, Zk, Zv);
        gemm_mfma<false, false><<<dim3(NM / 128, DD / 128), blk, 0, stream>>>(
            Zq, DD, wtO + (long)l * 65536, bo + (long)l * DD, res32, DD, DD);
        ln_residual<<<dim3(NM / 4), blk, 0, stream>>>(Abf, res32, g_ln1 + l * DD, b_ln1 + l * DD);
        for (int mr = 0; mr < NM / MR; ++mr) {
            const long r0 = (long)mr * MR;
            gemm_mfma<true, true><<<dim3(MR / 128, FFD / 128), blk, 0, stream>>>(
                Abf + r0 * DD, DD, wtW1 + (long)l * 2048 * 256, b1 + (long)l * FFD, Hid, FFD, DD);
            gemm_mfma<false, false><<<dim3(MR / 128, DD / 128), blk, 0, stream>>>(
                Hid, FFD, wtW2 + (long)l * 256 * 2048, b2 + (long)l * DD, res32f, DD, FFD);
            ln_residual<<<dim3(MR / 4), blk, 0, stream>>>(
                Abf + r0 * DD, res32f, g_ln2 + l * DD, b_ln2 + l * DD);
        }
    }

    // ---- output head ----
    final_out<<<dim3(BN), blk, 0, stream>>>(Abf, W_out, b_out, out);
}

// Round 5
// 2758.410 us; speedup vs baseline: 8.0164x; 1.0679x over previous
//
#include <hip/hip_runtime.h>
#include <math.h>

// ---- problem constants ----
#define BB   8
#define TT   5
#define NN   2048
#define FIN  64
#define EE   32768
#define DD   256
#define HH   8
#define FFD  2048
#define NCLS 10
#define GG   (BB*TT)        // 40 graphs
#define BN   (BB*NN)        // 16384
#define NM   (GG*NN)        // 81920 rows (= TT*BN)
#define NE   ((long)GG*EE)  // 1310720 edges

#define MR        16384           // rows per FFN chunk (5 chunks)

typedef __attribute__((ext_vector_type(8))) short short8;
typedef __attribute__((ext_vector_type(4))) float f32x4;

// ---- bf16 helpers (RNE) ----
__device__ __forceinline__ unsigned short f2b(float f) {
    unsigned u = __float_as_uint(f);
    u = (u + 0x7fffu + ((u >> 16) & 1u)) >> 16;
    return (unsigned short)u;
}
__device__ __forceinline__ float b2f(unsigned short b) {
    return __uint_as_float(((unsigned)b) << 16);
}

// async global->LDS, 16B per lane (dest must be wave-uniform base + lane*16)
__device__ __forceinline__ void gload_lds16(const void* g, void* l) {
    __builtin_amdgcn_global_load_lds(
        (__attribute__((address_space(1))) void*)g,
        (__attribute__((address_space(3))) void*)l, 16, 0, 0);
}

// =====================================================================
// Weight transpose+convert: in fp32 [K][N] row-major -> out bf16 [N][K]
// =====================================================================
__global__ void wtrans(const float* __restrict__ in, unsigned short* __restrict__ out,
                       int K, int N) {
    __shared__ float t[32][33];
    const int n0 = blockIdx.x * 32, k0 = blockIdx.y * 32;
    const int tx = threadIdx.x, ty = threadIdx.y;
    for (int i = ty; i < 32; i += 8) t[i][tx] = in[(long)(k0 + i) * N + n0 + tx];
    __syncthreads();
    for (int i = ty; i < 32; i += 8)
        out[(long)(n0 + i) * K + k0 + tx] = f2b(t[tx][i]);
}

// fp32 -> bf16 elementwise (n4 float4 groups)
__global__ void xconvert(const float* __restrict__ in, unsigned short* __restrict__ out, long n4) {
    long gid = (long)blockIdx.x * blockDim.x + threadIdx.x;
    if (gid >= n4) return;
    float4 v = ((const float4*)in)[gid];
    ushort4 o;
    o.x = f2b(v.x); o.y = f2b(v.y); o.z = f2b(v.z); o.w = f2b(v.w);
    ((ushort4*)out)[gid] = o;
}

// =====================================================================
// bf16 MFMA GEMM (m97 structure): C[M x N] = A[M x K] @ W[K x N] + bias
// A bf16 row-major (lda), WT = W^T bf16 [N][K], C fp32 or bf16 (ldc).
// 128x128 tile, BK=32, 256 threads = 4 waves (2x2), 16x16x32 MFMA.
// Staging via global_load_lds width=16 into linear [128][32] LDS.
// =====================================================================
template <bool RELU, bool OUTBF>
__global__ __launch_bounds__(256) void gemm_mfma(
    const unsigned short* __restrict__ A, int lda,
    const unsigned short* __restrict__ WT,
    const float* __restrict__ bias,
    void* __restrict__ Cv, int ldc, int K)
{
    __shared__ unsigned short As[128 * 32];
    __shared__ unsigned short Bs[128 * 32];
    const int tid = threadIdx.x;
    const int wid = tid >> 6, lane = tid & 63;
    const int wm = wid >> 1, wn = wid & 1;
    const long row0 = (long)blockIdx.x * 128;
    const long col0 = (long)blockIdx.y * 128;
    const int srow = tid >> 2;            // 0..63 (two row-blocks of 64)
    const int scol = (tid & 3) * 8;       // 0,8,16,24 (elements)
    const int kb = (lane >> 4) * 8;
    const int fr = lane & 15;
    f32x4 acc[4][4] = {};
    const unsigned short* Ag = &A[(row0 + srow) * (long)lda + scol];
    const unsigned short* Bg = &WT[(col0 + srow) * (long)K + scol];
    unsigned short* Al = &As[srow * 32 + scol];
    unsigned short* Bl = &Bs[srow * 32 + scol];
    for (int k0 = 0; k0 < K; k0 += 32) {
        __syncthreads();
        gload_lds16(Ag + k0, Al);
        gload_lds16(Ag + (long)64 * lda + k0, Al + 64 * 32);
        gload_lds16(Bg + k0, Bl);
        gload_lds16(Bg + (long)64 * K + k0, Bl + 64 * 32);
        __syncthreads();
        short8 af[4], bfr[4];
#pragma unroll
        for (int mf = 0; mf < 4; ++mf)
            af[mf] = *(const short8*)&As[(wm * 64 + mf * 16 + fr) * 32 + kb];
#pragma unroll
        for (int nf = 0; nf < 4; ++nf)
            bfr[nf] = *(const short8*)&Bs[(wn * 64 + nf * 16 + fr) * 32 + kb];
#pragma unroll
        for (int mf = 0; mf < 4; ++mf)
#pragma unroll
            for (int nf = 0; nf < 4; ++nf)
                acc[mf][nf] = __builtin_amdgcn_mfma_f32_16x16x32_bf16(
                    af[mf], bfr[nf], acc[mf][nf], 0, 0, 0);
    }
    const int fq = lane >> 4;
#pragma unroll
    for (int nf = 0; nf < 4; ++nf) {
        const long col = col0 + wn * 64 + nf * 16 + fr;
        const float bv = bias[col];
#pragma unroll
        for (int mf = 0; mf < 4; ++mf) {
#pragma unroll
            for (int i = 0; i < 4; ++i) {
                const long r = row0 + wm * 64 + mf * 16 + fq * 4 + i;
                float vv = acc[mf][nf][i] + bv;
                if (RELU) vv = fmaxf(vv, 0.f);
                if (OUTBF) ((unsigned short*)Cv)[r * ldc + col] = f2b(vv);
                else       ((float*)Cv)[r * ldc + col] = vv;
            }
        }
    }
}

// =====================================================================
// CSR build: edges grouped by global target row tf = g*NN + tgt
// =====================================================================
__global__ void csr_init(int* __restrict__ cnt, int* __restrict__ fill) {
    int gid = blockIdx.x * blockDim.x + threadIdx.x;
    if (gid < NM) { cnt[gid] = 0; fill[gid] = 0; }
}

__global__ void csr_count(const int* __restrict__ eidx, int* __restrict__ cnt) {
    long el = (long)blockIdx.x * blockDim.x + threadIdx.x;
    if (el >= NE) return;
    int g = (int)(el >> 15), e = (int)(el & (EE - 1));
    int tgt = eidx[((long)g * 2 + 1) * EE + e];
    atomicAdd(&cnt[g * NN + tgt], 1);
}

// single-block exclusive scan over NM counts (1024 threads x 80 each)
__global__ __launch_bounds__(1024) void csr_scan(const int* __restrict__ cnt, int* __restrict__ off) {
    __shared__ int part[1024];
    const int t = threadIdx.x;
    const int base = t * (NM / 1024);
    int s = 0;
    for (int i = 0; i < NM / 1024; ++i) s += cnt[base + i];
    part[t] = s;
    __syncthreads();
    for (int d = 1; d < 1024; d <<= 1) {
        int v = (t >= d) ? part[t - d] : 0;
        __syncthreads();
        part[t] += v;
        __syncthreads();
    }
    int run = (t == 0) ? 0 : part[t - 1];
    for (int i = 0; i < NM / 1024; ++i) { off[base + i] = run; run += cnt[base + i]; }
    if (t == 1023) off[NM] = run;
}

__global__ void csr_scatter(const int* __restrict__ eidx, const int* __restrict__ off,
                            int* __restrict__ fill, int* __restrict__ csr) {
    long el = (long)blockIdx.x * blockDim.x + threadIdx.x;
    if (el >= NE) return;
    int g = (int)(el >> 15), e = (int)(el & (EE - 1));
    int tgt = eidx[((long)g * 2 + 1) * EE + e];
    int tf = g * NN + tgt;
    int pos = atomicAdd(&fill[tf], 1);
    csr[off[tf] + pos] = (int)el;
}

// =====================================================================
// Fused TransformerConv: one 64-lane wave per target node, CSR gather,
// online softmax, 2-deep software pipeline on the edge loop.
// Writes conv output (bf16) OVER the q buffer (each wave owns its row).
// =====================================================================
__global__ __launch_bounds__(256) void conv_fused(
    unsigned short* __restrict__ q, const unsigned short* __restrict__ k,
    const unsigned short* __restrict__ v,
    const int* __restrict__ eidx, const float* __restrict__ eattr,
    const float* __restrict__ W_edge, const float* __restrict__ b_edge,
    const int* __restrict__ off, const int* __restrict__ csr)
{
    const int tid = threadIdx.x;
    const int wave = tid >> 6, lane = tid & 63;
    const long tf = (long)blockIdx.x * 4 + wave;
    const int d0 = lane * 4;
    const ushort4 q4 = *(const ushort4*)&q[tf * 256 + d0];
    const float q0 = b2f(q4.x), q1 = b2f(q4.y), q2 = b2f(q4.z), q3 = b2f(q4.w);
    const float be0 = b_edge[d0], be1 = b_edge[d0 + 1],
                be2 = b_edge[d0 + 2], be3 = b_edge[d0 + 3];
    float w0[6], w1r[6], w2r[6], w3r[6];
#pragma unroll
    for (int j2 = 0; j2 < 6; ++j2) {
        const float* wp = &W_edge[j2 * 256 + d0];
        w0[j2] = wp[0]; w1r[j2] = wp[1]; w2r[j2] = wp[2]; w3r[j2] = wp[3];
    }
    const float scale = 0.17677669529663687f;  // 1/sqrt(32)
    float m = -1e30f, s = 0.f;
    float a0 = 0.f, a1 = 0.f, a2 = 0.f, a3 = 0.f;
    const int jb = off[tf], je = off[tf + 1];
    ushort4 kc, vc; float eac[6];
    if (jb < je) {
        const int el = csr[jb];
        const int g = el >> 15, e = el & (EE - 1);
        const int src = eidx[((long)g * 2) * EE + e];
        const long sf = (long)g * NN + src;
        kc = *(const ushort4*)&k[sf * 256 + d0];
        vc = *(const ushort4*)&v[sf * 256 + d0];
#pragma unroll
        for (int t = 0; t < 6; ++t) eac[t] = eattr[(long)el * 6 + t];
    }
    for (int j = jb; j < je; ++j) {
        ushort4 kn, vn; float ean[6];
        if (j + 1 < je) {  // prefetch next edge (wave-uniform branch)
            const int el = csr[j + 1];
            const int g = el >> 15, e = el & (EE - 1);
            const int src = eidx[((long)g * 2) * EE + e];
            const long sf = (long)g * NN + src;
            kn = *(const ushort4*)&k[sf * 256 + d0];
            vn = *(const ushort4*)&v[sf * 256 + d0];
#pragma unroll
            for (int t = 0; t < 6; ++t) ean[t] = eattr[(long)el * 6 + t];
        }
        float ef0 = be0, ef1 = be1, ef2 = be2, ef3 = be3;
#pragma unroll
        for (int j2 = 0; j2 < 6; ++j2) {
            ef0 += eac[j2] * w0[j2]; ef1 += eac[j2] * w1r[j2];
            ef2 += eac[j2] * w2r[j2]; ef3 += eac[j2] * w3r[j2];
        }
        float p = q0 * (b2f(kc.x) + ef0) + q1 * (b2f(kc.y) + ef1)
                + q2 * (b2f(kc.z) + ef2) + q3 * (b2f(kc.w) + ef3);
        p += __shfl_xor(p, 1, 64);
        p += __shfl_xor(p, 2, 64);
        p += __shfl_xor(p, 4, 64);   // 8-lane group = one head (32 dims)
        const float a = p * scale;
        const float nm = fmaxf(m, a);
        const float r = __expf(m - nm);
        const float w = __expf(a - nm);
        s = s * r + w;
        a0 = a0 * r + w * (b2f(vc.x) + ef0);
        a1 = a1 * r + w * (b2f(vc.y) + ef1);
        a2 = a2 * r + w * (b2f(vc.z) + ef2);
        a3 = a3 * r + w * (b2f(vc.w) + ef3);
        m = nm;
        kc = kn; vc = vn;
#pragma unroll
        for (int t = 0; t < 6; ++t) eac[t] = ean[t];
    }
    const float inv = (s > 0.f) ? 1.f / s : 0.f;
    ushort4 o;
    o.x = f2b(a0 * inv); o.y = f2b(a1 * inv);
    o.z = f2b(a2 * inv); o.w = f2b(a3 * inv);
    *(ushort4*)&q[tf * 256 + d0] = o;
}

// seq(bf16, [t*BN+b*N+n]) = conv(bf16, [(b*T+t)*N+n]) + skip(bf16, same layout)
__global__ void transpose_add(const unsigned short* __restrict__ conv,
                              const unsigned short* __restrict__ skip,
                              unsigned short* __restrict__ out) {
    long gid = (long)blockIdx.x * blockDim.x + threadIdx.x;  // NM*64 ushort4s
    long row = gid >> 6;
    int c4 = (int)(gid & 63);
    int n = (int)(row % NN);
    int bt = (int)(row / NN);
    int t = bt % TT, b = bt / TT;
    long orow = (long)t * BN + (long)b * NN + n;
    ushort4 cv = ((const ushort4*)conv)[row * 64 + c4];
    ushort4 sv = ((const ushort4*)skip)[row * 64 + c4];
    ushort4 o;
    o.x = f2b(b2f(cv.x) + b2f(sv.x));
    o.y = f2b(b2f(cv.y) + b2f(sv.y));
    o.z = f2b(b2f(cv.z) + b2f(sv.z));
    o.w = f2b(b2f(cv.w) + b2f(sv.w));
    ((ushort4*)out)[orow * 64 + c4] = o;
}

// temporal attention over T=5 (bf16 q/k/v; o written in-place over q).
__global__ __launch_bounds__(256) void mha_time(
    unsigned short* __restrict__ q, const unsigned short* __restrict__ k,
    const unsigned short* __restrict__ v)
{
    const int tid = threadIdx.x;
    const int grp = tid >> 5, c = tid & 31;
    long pair = (long)blockIdx.x * 8 + grp;   // BN*HH pairs
    int h = (int)(pair & 7);
    long bn = pair >> 3;
    const float scale = 0.17677669529663687f;
    float qv[TT], kv[TT], vv[TT];
    long r[TT];
#pragma unroll
    for (int t = 0; t < TT; ++t) {
        r[t] = ((long)t * BN + bn) * 256 + h * 32 + c;
        qv[t] = b2f(q[r[t]]); kv[t] = b2f(k[r[t]]); vv[t] = b2f(v[r[t]]);
    }
    float s[TT][TT];
#pragma unroll
    for (int t = 0; t < TT; ++t)
#pragma unroll
        for (int u = 0; u < TT; ++u) {
            float p = qv[t] * kv[u];
#pragma unroll
            for (int m = 16; m >= 1; m >>= 1) p += __shfl_xor(p, m, 64);
            s[t][u] = p * scale;
        }
#pragma unroll
    for (int t = 0; t < TT; ++t) {
        float mx = s[t][0];
#pragma unroll
        for (int u = 1; u < TT; ++u) mx = fmaxf(mx, s[t][u]);
        float sm = 0.f;
#pragma unroll
        for (int u = 0; u < TT; ++u) { s[t][u] = expf(s[t][u] - mx); sm += s[t][u]; }
        float inv = 1.f / sm;
        float o = 0.f;
#pragma unroll
        for (int u = 0; u < TT; ++u) o += s[t][u] * vv[u];
        q[r[t]] = f2b(o * inv);
    }
}

// seq(bf16) = LayerNorm(seq + res(fp32)) * g + b; one wave per row
__global__ __launch_bounds__(256) void ln_residual(
    unsigned short* __restrict__ seq, const float* __restrict__ res,
    const float* __restrict__ g, const float* __restrict__ b)
{
    const int wave = threadIdx.x >> 6, lane = threadIdx.x & 63;
    long row = (long)blockIdx.x * 4 + wave;
    const ushort4 s4 = *(const ushort4*)&seq[row * 256 + lane * 4];
    const float4 r4 = *(const float4*)&res[row * 256 + lane * 4];
    float x[4] = { b2f(s4.x) + r4.x, b2f(s4.y) + r4.y, b2f(s4.z) + r4.z, b2f(s4.w) + r4.w };
    float sum = x[0] + x[1] + x[2] + x[3];
#pragma unroll
    for (int m = 32; m >= 1; m >>= 1) sum += __shfl_xor(sum, m, 64);
    float mean = sum * (1.f / 256.f);
    float vs = 0.f;
#pragma unroll
    for (int i = 0; i < 4; ++i) { float dl = x[i] - mean; vs += dl * dl; }
#pragma unroll
    for (int m = 32; m >= 1; m >>= 1) vs += __shfl_xor(vs, m, 64);
    float inv = rsqrtf(vs * (1.f / 256.f) + 1e-5f);
    ushort4 o;
    float* gp = (float*)g;
    o.x = f2b((x[0] - mean) * inv * gp[lane * 4 + 0] + b[lane * 4 + 0]);
    o.y = f2b((x[1] - mean) * inv * gp[lane * 4 + 1] + b[lane * 4 + 1]);
    o.z = f2b((x[2] - mean) * inv * gp[lane * 4 + 2] + b[lane * 4 + 2]);
    o.w = f2b((x[3] - mean) * inv * gp[lane * 4 + 3] + b[lane * 4 + 3]);
    *(ushort4*)&seq[row * 256 + lane * 4] = o;
}

// out[row][0..9] = seq[t=T-1 rows](bf16) @ W_out + b_out ; one block per row
__global__ __launch_bounds__(256) void final_out(
    const unsigned short* __restrict__ seq, const float* __restrict__ Wd,
    const float* __restrict__ bd, float* __restrict__ out)
{
    __shared__ float xs[256];
    long row = blockIdx.x;
    xs[threadIdx.x] = b2f(seq[((long)(TT - 1) * BN + row) * 256 + threadIdx.x]);
    __syncthreads();
    const int wv = threadIdx.x >> 6, lane = threadIdx.x & 63;
    for (int o = wv; o < NCLS; o += 4) {
        float p = 0.f;
#pragma unroll
        for (int i = 0; i < 4; ++i) {
            int kk = lane + 64 * i;
            p += xs[kk] * Wd[kk * NCLS + o];
        }
#pragma unroll
        for (int m = 32; m >= 1; m >>= 1) p += __shfl_xor(p, m, 64);
        if (lane == 0) out[row * NCLS + o] = p + bd[o];
    }
}

__global__ void fill_sentinel(float* __restrict__ out, int n) {
    int gid = blockIdx.x * blockDim.x + threadIdx.x;
    if (gid < n) out[gid] = 1.0e6f;
}

// =====================================================================
extern "C" void kernel_launch(void* const* d_in, const int* in_sizes, int n_in,
                              void* d_out, int out_size, void* d_ws, size_t ws_size,
                              hipStream_t stream) {
    const float* xseq  = (const float*)d_in[0];
    const int*   eidx  = (const int*)d_in[1];
    const float* eattr = (const float*)d_in[2];
    const float* W_node = (const float*)d_in[3];
    const float* b_node = (const float*)d_in[4];
    const float* W_edge = (const float*)d_in[5];
    const float* b_edge = (const float*)d_in[6];
    const float* Wq = (const float*)d_in[7];  const float* bq = (const float*)d_in[8];
    const float* Wk = (const float*)d_in[9];  const float* bk = (const float*)d_in[10];
    const float* Wv = (const float*)d_in[11]; const float* bv = (const float*)d_in[12];
    const float* Ws = (const float*)d_in[13]; const float* bs = (const float*)d_in[14];
    const float* Wqkv = (const float*)d_in[15]; const float* bqkv = (const float*)d_in[16];
    const float* Wo = (const float*)d_in[17];   const float* bo = (const float*)d_in[18];
    const float* W1 = (const float*)d_in[19];   const float* b1 = (const float*)d_in[20];
    const float* W2 = (const float*)d_in[21];   const float* b2 = (const float*)d_in[22];
    const float* g_ln1 = (const float*)d_in[23]; const float* b_ln1 = (const float*)d_in[24];
    const float* g_ln2 = (const float*)d_in[25]; const float* b_ln2 = (const float*)d_in[26];
    const float* W_out = (const float*)d_in[27]; const float* b_out = (const float*)d_in[28];
    float* out = (float*)d_out;

    // ---- workspace layout ----
    const long SZ = (long)NM * DD;            // 20,971,520 elements
    unsigned short* Abf = (unsigned short*)d_ws;     // seq activations bf16 (40MB)
    unsigned short* Zu  = Abf + SZ;                  // Z region: 3*SZ ushorts (120MB)
    unsigned short* Zq = Zu;                 // q -> conv out (in-place)
    unsigned short* Zk = Zu + SZ;            // k -> skip
    unsigned short* Zv = Zu + 2 * SZ;        // v
    float* res32 = (float*)(Zu + SZ);        // Wo-out residual fp32 (80MB, over K+V)
    unsigned short* Hid = Zu + SZ;           // FFN hidden bf16 [MR][2048] (64MB)
    float* res32f = (float*)(Zu + SZ + 33554432);   // FFN residual fp32 [MR][256] (16MB)
    // weights region after Z:
    unsigned short* WX = Zu + 3 * SZ;
    unsigned short* xbf = WX;                             // 81920*64
    unsigned short* wtN = xbf + (long)NM * FIN;           // [256][64]
    unsigned short* wtQ = wtN + 256 * 64;
    unsigned short* wtK = wtQ + 65536;
    unsigned short* wtV = wtK + 65536;
    unsigned short* wtS = wtV + 65536;
    unsigned short* wtQKV = wtS + 65536;                  // 3 * [768][256]
    unsigned short* wtO = wtQKV + 3L * 768 * 256;         // 3 * [256][256]
    unsigned short* wtW1 = wtO + 3L * 65536;              // 3 * [2048][256]
    unsigned short* wtW2 = wtW1 + 3L * 2048 * 256;        // 3 * [256][2048]
    // CSR region
    int* cnt  = (int*)(wtW2 + 3L * 256 * 2048);
    int* coff = cnt + NM;                                 // NM+1
    int* cfil = coff + NM + 1;
    int* csr  = cfil + NM;                                // NE ints
    char* wend = (char*)(csr + NE);
    const size_t need = (size_t)(wend - (char*)d_ws);
    if (ws_size < need) {
        fill_sentinel<<<dim3((out_size + 255) / 256), dim3(256), 0, stream>>>(out, out_size);
        return;
    }

    dim3 blk(256);
    dim3 tb(32, 8);

    // ---- prologue: convert weights (fp32 [K][N] -> bf16 [N][K]) and x ----
    xconvert<<<dim3((unsigned)((long)NM * FIN / 4 / 256)), blk, 0, stream>>>(xseq, xbf, (long)NM * FIN / 4);
    wtrans<<<dim3(DD / 32, FIN / 32), tb, 0, stream>>>(W_node, wtN, FIN, DD);
    wtrans<<<dim3(DD / 32, DD / 32), tb, 0, stream>>>(Wq, wtQ, DD, DD);
    wtrans<<<dim3(DD / 32, DD / 32), tb, 0, stream>>>(Wk, wtK, DD, DD);
    wtrans<<<dim3(DD / 32, DD / 32), tb, 0, stream>>>(Wv, wtV, DD, DD);
    wtrans<<<dim3(DD / 32, DD / 32), tb, 0, stream>>>(Ws, wtS, DD, DD);
    for (int l = 0; l < 3; ++l) {
        wtrans<<<dim3(768 / 32, DD / 32), tb, 0, stream>>>(Wqkv + (long)l * DD * 768, wtQKV + (long)l * 768 * 256, DD, 768);
        wtrans<<<dim3(DD / 32, DD / 32), tb, 0, stream>>>(Wo + (long)l * DD * DD, wtO + (long)l * 65536, DD, DD);
        wtrans<<<dim3(FFD / 32, DD / 32), tb, 0, stream>>>(W1 + (long)l * DD * FFD, wtW1 + (long)l * 2048 * 256, DD, FFD);
        wtrans<<<dim3(DD / 32, FFD / 32), tb, 0, stream>>>(W2 + (long)l * FFD * DD, wtW2 + (long)l * 256 * 2048, FFD, DD);
    }

    // ---- CSR build (independent of GEMMs) ----
    csr_init<<<dim3((NM + 255) / 256), blk, 0, stream>>>(cnt, cfil);
    csr_count<<<dim3((unsigned)(NE / 256)), blk, 0, stream>>>(eidx, cnt);
    csr_scan<<<dim3(1), dim3(1024), 0, stream>>>(cnt, coff);
    csr_scatter<<<dim3((unsigned)(NE / 256)), blk, 0, stream>>>(eidx, coff, cfil, csr);

    // ---- stage 1: h, q/k/v, fused conv, skip, transpose+add ----
    gemm_mfma<false, true><<<dim3(NM / 128, DD / 128), blk, 0, stream>>>(
        xbf, FIN, wtN, b_node, Abf, DD, FIN);
    gemm_mfma<false, true><<<dim3(NM / 128, DD / 128), blk, 0, stream>>>(
        Abf, DD, wtQ, bq, Zq, DD, DD);
    gemm_mfma<false, true><<<dim3(NM / 128, DD / 128), blk, 0, stream>>>(
        Abf, DD, wtK, bk, Zk, DD, DD);
    gemm_mfma<false, true><<<dim3(NM / 128, DD / 128), blk, 0, stream>>>(
        Abf, DD, wtV, bv, Zv, DD, DD);
    conv_fused<<<dim3(NM / 4), blk, 0, stream>>>(
        Zq, Zk, Zv, eidx, eattr, W_edge, b_edge, coff, csr);
    gemm_mfma<false, true><<<dim3(NM / 128, DD / 128), blk, 0, stream>>>(
        Abf, DD, wtS, bs, Zk, DD, DD);                  // skip over dead k
    transpose_add<<<dim3(NM * 64 / 256), blk, 0, stream>>>(Zq, Zk, Abf);

    // ---- stage 2: 3 temporal transformer encoder layers ----
    for (int l = 0; l < 3; ++l) {
        const unsigned short* wql = wtQKV + (long)l * 768 * 256;
        const float* bl = bqkv + (long)l * 768;
        gemm_mfma<false, true><<<dim3(NM / 128, DD / 128), blk, 0, stream>>>(
            Abf, DD, wql + 0 * 256 * 256, bl + 0, Zq, DD, DD);
        gemm_mfma<false, true><<<dim3(NM / 128, DD / 128), blk, 0, stream>>>(
            Abf, DD, wql + 1L * 256 * 256, bl + 256, Zk, DD, DD);
        gemm_mfma<false, true><<<dim3(NM / 128, DD / 128), blk, 0, stream>>>(
            Abf, DD, wql + 2L * 256 * 256, bl + 512, Zv, DD, DD);
        mha_time<<<dim3(BN * HH / 8), blk, 0, stream>>>(Zq, Zk, Zv);
        gemm_mfma<false, false><<<dim3(NM / 128, DD / 128), blk, 0, stream>>>(
            Zq, DD, wtO + (long)l * 65536, bo + (long)l * DD, res32, DD, DD);
        ln_residual<<<dim3(NM / 4), blk, 0, stream>>>(Abf, res32, g_ln1 + l * DD, b_ln1 + l * DD);
        for (int mr = 0; mr < NM / MR; ++mr) {
            const long r0 = (long)mr * MR;
            gemm_mfma<true, true><<<dim3(MR / 128, FFD / 128), blk, 0, stream>>>(
                Abf + r0 * DD, DD, wtW1 + (long)l * 2048 * 256, b1 + (long)l * FFD, Hid, FFD, DD);
            gemm_mfma<false, false><<<dim3(MR / 128, DD / 128), blk, 0, stream>>>(
                Hid, FFD, wtW2 + (long)l * 256 * 2048, b2 + (long)l * DD, res32f, DD, FFD);
            ln_residual<<<dim3(MR / 4), blk, 0, stream>>>(
                Abf + r0 * DD, res32f, g_ln2 + l * DD, b_ln2 + l * DD);
        }
    }

    // ---- output head ----
    final_out<<<dim3(BN), blk, 0, stream>>>(Abf, W_out, b_out, out);
}

// Round 6
// 2551.104 us; speedup vs baseline: 8.6678x; 1.0813x over previous
//
#include <hip/hip_runtime.h>
#include <math.h>

// ---- problem constants ----
#define BB   8
#define TT   5
#define NN   2048
#define FIN  64
#define EE   32768
#define DD   256
#define HH   8
#define FFD  2048
#define NCLS 10
#define GG   (BB*TT)        // 40 graphs
#define BN   (BB*NN)        // 16384
#define NM   (GG*NN)        // 81920 rows (= TT*BN)
#define NE   ((long)GG*EE)  // 1310720 edges

#define MR        16384           // rows per FFN chunk (5 chunks)

typedef __attribute__((ext_vector_type(8))) short short8;
typedef __attribute__((ext_vector_type(4))) float f32x4;

// ---- bf16 helpers (RNE) ----
__device__ __forceinline__ unsigned short f2b(float f) {
    unsigned u = __float_as_uint(f);
    u = (u + 0x7fffu + ((u >> 16) & 1u)) >> 16;
    return (unsigned short)u;
}
__device__ __forceinline__ float b2f(unsigned short b) {
    return __uint_as_float(((unsigned)b) << 16);
}

// async global->LDS, 16B per lane (dest must be wave-uniform base + lane*16)
__device__ __forceinline__ void gload_lds16(const void* g, void* l) {
    __builtin_amdgcn_global_load_lds(
        (__attribute__((address_space(1))) void*)g,
        (__attribute__((address_space(3))) void*)l, 16, 0, 0);
}

// =====================================================================
// Weight transpose+convert: in fp32 [K][N] row-major -> out bf16 [N][K]
// =====================================================================
__global__ void wtrans(const float* __restrict__ in, unsigned short* __restrict__ out,
                       int K, int N) {
    __shared__ float t[32][33];
    const int n0 = blockIdx.x * 32, k0 = blockIdx.y * 32;
    const int tx = threadIdx.x, ty = threadIdx.y;
    for (int i = ty; i < 32; i += 8) t[i][tx] = in[(long)(k0 + i) * N + n0 + tx];
    __syncthreads();
    for (int i = ty; i < 32; i += 8)
        out[(long)(n0 + i) * K + k0 + tx] = f2b(t[tx][i]);
}

// fp32 -> bf16 elementwise (n4 float4 groups)
__global__ void xconvert(const float* __restrict__ in, unsigned short* __restrict__ out, long n4) {
    long gid = (long)blockIdx.x * blockDim.x + threadIdx.x;
    if (gid >= n4) return;
    float4 v = ((const float4*)in)[gid];
    ushort4 o;
    o.x = f2b(v.x); o.y = f2b(v.y); o.z = f2b(v.z); o.w = f2b(v.w);
    ((ushort4*)out)[gid] = o;
}

// =====================================================================
// bf16 MFMA GEMM (m97 structure + XCD swizzle):
// C[M x N] = A[M x K] @ W[K x N] + bias
// A bf16 row-major (lda), WT = W^T bf16 [N][K], C fp32 or bf16 (ldc).
// 128x128 tile, BK=32, 256 threads = 4 waves (2x2), 16x16x32 MFMA.
// =====================================================================
template <bool RELU, bool OUTBF>
__global__ __launch_bounds__(256) void gemm_mfma(
    const unsigned short* __restrict__ A, int lda,
    const unsigned short* __restrict__ WT,
    const float* __restrict__ bias,
    void* __restrict__ Cv, int ldc, int K)
{
    __shared__ unsigned short As[128 * 32];
    __shared__ unsigned short Bs[128 * 32];
    const int tid = threadIdx.x;
    const int wid = tid >> 6, lane = tid & 63;
    const int wm = wid >> 1, wn = wid & 1;
    // XCD-chunked bijective swizzle: each XCD owns an M-chunk x all N,
    // y fastest within chunk (A-panel read once per XCD; W panels L2-hot).
    const int gx = gridDim.x, gy = gridDim.y;
    int bx = blockIdx.x, by = blockIdx.y;
    if ((gx & 7) == 0) {
        const int lbid = bx + gx * by;
        const int xcd = lbid & 7;
        const int i = lbid >> 3;
        const int CX = gx >> 3;
        bx = xcd * CX + i / gy;
        by = i - (i / gy) * gy;
    }
    const long row0 = (long)bx * 128;
    const long col0 = (long)by * 128;
    const int srow = tid >> 2;            // 0..63 (two row-blocks of 64)
    const int scol = (tid & 3) * 8;       // 0,8,16,24 (elements)
    const int kb = (lane >> 4) * 8;
    const int fr = lane & 15;
    f32x4 acc[4][4] = {};
    const unsigned short* Ag = &A[(row0 + srow) * (long)lda + scol];
    const unsigned short* Bg = &WT[(col0 + srow) * (long)K + scol];
    unsigned short* Al = &As[srow * 32 + scol];
    unsigned short* Bl = &Bs[srow * 32 + scol];
    for (int k0 = 0; k0 < K; k0 += 32) {
        __syncthreads();
        gload_lds16(Ag + k0, Al);
        gload_lds16(Ag + (long)64 * lda + k0, Al + 64 * 32);
        gload_lds16(Bg + k0, Bl);
        gload_lds16(Bg + (long)64 * K + k0, Bl + 64 * 32);
        __syncthreads();
        short8 af[4], bfr[4];
#pragma unroll
        for (int mf = 0; mf < 4; ++mf)
            af[mf] = *(const short8*)&As[(wm * 64 + mf * 16 + fr) * 32 + kb];
#pragma unroll
        for (int nf = 0; nf < 4; ++nf)
            bfr[nf] = *(const short8*)&Bs[(wn * 64 + nf * 16 + fr) * 32 + kb];
#pragma unroll
        for (int mf = 0; mf < 4; ++mf)
#pragma unroll
            for (int nf = 0; nf < 4; ++nf)
                acc[mf][nf] = __builtin_amdgcn_mfma_f32_16x16x32_bf16(
                    af[mf], bfr[nf], acc[mf][nf], 0, 0, 0);
    }
    const int fq = lane >> 4;
#pragma unroll
    for (int nf = 0; nf < 4; ++nf) {
        const long col = col0 + wn * 64 + nf * 16 + fr;
        const float bv = bias[col];
#pragma unroll
        for (int mf = 0; mf < 4; ++mf) {
#pragma unroll
            for (int i = 0; i < 4; ++i) {
                const long r = row0 + wm * 64 + mf * 16 + fq * 4 + i;
                float vv = acc[mf][nf][i] + bv;
                if (RELU) vv = fmaxf(vv, 0.f);
                if (OUTBF) ((unsigned short*)Cv)[r * ldc + col] = f2b(vv);
                else       ((float*)Cv)[r * ldc + col] = vv;
            }
        }
    }
}

// =====================================================================
// CSR build: edges grouped by global target row tf = g*NN + tgt
// =====================================================================
__global__ void csr_init(int* __restrict__ cnt, int* __restrict__ fill) {
    int gid = blockIdx.x * blockDim.x + threadIdx.x;
    if (gid < NM) { cnt[gid] = 0; fill[gid] = 0; }
}

__global__ void csr_count(const int* __restrict__ eidx, int* __restrict__ cnt) {
    long el = (long)blockIdx.x * blockDim.x + threadIdx.x;
    if (el >= NE) return;
    int g = (int)(el >> 15), e = (int)(el & (EE - 1));
    int tgt = eidx[((long)g * 2 + 1) * EE + e];
    atomicAdd(&cnt[g * NN + tgt], 1);
}

// single-block exclusive scan over NM counts (1024 threads x 80 each)
__global__ __launch_bounds__(1024) void csr_scan(const int* __restrict__ cnt, int* __restrict__ off) {
    __shared__ int part[1024];
    const int t = threadIdx.x;
    const int base = t * (NM / 1024);
    int s = 0;
    for (int i = 0; i < NM / 1024; ++i) s += cnt[base + i];
    part[t] = s;
    __syncthreads();
    for (int d = 1; d < 1024; d <<= 1) {
        int v = (t >= d) ? part[t - d] : 0;
        __syncthreads();
        part[t] += v;
        __syncthreads();
    }
    int run = (t == 0) ? 0 : part[t - 1];
    for (int i = 0; i < NM / 1024; ++i) { off[base + i] = run; run += cnt[base + i]; }
    if (t == 1023) off[NM] = run;
}

__global__ void csr_scatter(const int* __restrict__ eidx, const int* __restrict__ off,
                            int* __restrict__ fill, int* __restrict__ csr) {
    long el = (long)blockIdx.x * blockDim.x + threadIdx.x;
    if (el >= NE) return;
    int g = (int)(el >> 15), e = (int)(el & (EE - 1));
    int tgt = eidx[((long)g * 2 + 1) * EE + e];
    int tf = g * NN + tgt;
    int pos = atomicAdd(&fill[tf], 1);
    csr[off[tf] + pos] = (int)el;
}

// =====================================================================
// Fused TransformerConv: one 64-lane wave per target node, CSR gather,
// online softmax, 2-deep software pipeline. XCD-chunked swizzle keeps
// each graph's k/v working set (4MB) inside one XCD's L2.
// Writes conv output (bf16) OVER the q buffer (each wave owns its row).
// =====================================================================
__global__ __launch_bounds__(256) void conv_fused(
    unsigned short* __restrict__ q, const unsigned short* __restrict__ k,
    const unsigned short* __restrict__ v,
    const int* __restrict__ eidx, const float* __restrict__ eattr,
    const float* __restrict__ W_edge, const float* __restrict__ b_edge,
    const int* __restrict__ off, const int* __restrict__ csr)
{
    const int tid = threadIdx.x;
    const int wave = tid >> 6, lane = tid & 63;
    // bijective XCD swizzle: 20480 blocks -> each XCD gets 2560 contiguous (5 graphs)
    const int bid = (blockIdx.x & 7) * (NM / 4 / 8) + (blockIdx.x >> 3);
    const long tf = (long)bid * 4 + wave;
    const int d0 = lane * 4;
    const ushort4 q4 = *(const ushort4*)&q[tf * 256 + d0];
    const float q0 = b2f(q4.x), q1 = b2f(q4.y), q2 = b2f(q4.z), q3 = b2f(q4.w);
    const float be0 = b_edge[d0], be1 = b_edge[d0 + 1],
                be2 = b_edge[d0 + 2], be3 = b_edge[d0 + 3];
    float w0[6], w1r[6], w2r[6], w3r[6];
#pragma unroll
    for (int j2 = 0; j2 < 6; ++j2) {
        const float* wp = &W_edge[j2 * 256 + d0];
        w0[j2] = wp[0]; w1r[j2] = wp[1]; w2r[j2] = wp[2]; w3r[j2] = wp[3];
    }
    const float scale = 0.17677669529663687f;  // 1/sqrt(32)
    float m = -1e30f, s = 0.f;
    float a0 = 0.f, a1 = 0.f, a2 = 0.f, a3 = 0.f;
    const int jb = off[tf], je = off[tf + 1];
    ushort4 kc, vc; float eac[6];
    if (jb < je) {
        const int el = csr[jb];
        const int g = el >> 15, e = el & (EE - 1);
        const int src = eidx[((long)g * 2) * EE + e];
        const long sf = (long)g * NN + src;
        kc = *(const ushort4*)&k[sf * 256 + d0];
        vc = *(const ushort4*)&v[sf * 256 + d0];
#pragma unroll
        for (int t = 0; t < 6; ++t) eac[t] = eattr[(long)el * 6 + t];
    }
    for (int j = jb; j < je; ++j) {
        ushort4 kn, vn; float ean[6];
        if (j + 1 < je) {  // prefetch next edge (wave-uniform branch)
            const int el = csr[j + 1];
            const int g = el >> 15, e = el & (EE - 1);
            const int src = eidx[((long)g * 2) * EE + e];
            const long sf = (long)g * NN + src;
            kn = *(const ushort4*)&k[sf * 256 + d0];
            vn = *(const ushort4*)&v[sf * 256 + d0];
#pragma unroll
            for (int t = 0; t < 6; ++t) ean[t] = eattr[(long)el * 6 + t];
        }
        float ef0 = be0, ef1 = be1, ef2 = be2, ef3 = be3;
#pragma unroll
        for (int j2 = 0; j2 < 6; ++j2) {
            ef0 += eac[j2] * w0[j2]; ef1 += eac[j2] * w1r[j2];
            ef2 += eac[j2] * w2r[j2]; ef3 += eac[j2] * w3r[j2];
        }
        float p = q0 * (b2f(kc.x) + ef0) + q1 * (b2f(kc.y) + ef1)
                + q2 * (b2f(kc.z) + ef2) + q3 * (b2f(kc.w) + ef3);
        p += __shfl_xor(p, 1, 64);
        p += __shfl_xor(p, 2, 64);
        p += __shfl_xor(p, 4, 64);   // 8-lane group = one head (32 dims)
        const float a = p * scale;
        const float nm = fmaxf(m, a);
        const float r = __expf(m - nm);
        const float w = __expf(a - nm);
        s = s * r + w;
        a0 = a0 * r + w * (b2f(vc.x) + ef0);
        a1 = a1 * r + w * (b2f(vc.y) + ef1);
        a2 = a2 * r + w * (b2f(vc.z) + ef2);
        a3 = a3 * r + w * (b2f(vc.w) + ef3);
        m = nm;
        kc = kn; vc = vn;
#pragma unroll
        for (int t = 0; t < 6; ++t) eac[t] = ean[t];
    }
    const float inv = (s > 0.f) ? 1.f / s : 0.f;
    ushort4 o;
    o.x = f2b(a0 * inv); o.y = f2b(a1 * inv);
    o.z = f2b(a2 * inv); o.w = f2b(a3 * inv);
    *(ushort4*)&q[tf * 256 + d0] = o;
}

// seq(bf16, [t*BN+b*N+n]) = conv(bf16, [(b*T+t)*N+n]) + skip(bf16, same layout)
__global__ void transpose_add(const unsigned short* __restrict__ conv,
                              const unsigned short* __restrict__ skip,
                              unsigned short* __restrict__ out) {
    long gid = (long)blockIdx.x * blockDim.x + threadIdx.x;  // NM*64 ushort4s
    long row = gid >> 6;
    int c4 = (int)(gid & 63);
    int n = (int)(row % NN);
    int bt = (int)(row / NN);
    int t = bt % TT, b = bt / TT;
    long orow = (long)t * BN + (long)b * NN + n;
    ushort4 cv = ((const ushort4*)conv)[row * 64 + c4];
    ushort4 sv = ((const ushort4*)skip)[row * 64 + c4];
    ushort4 o;
    o.x = f2b(b2f(cv.x) + b2f(sv.x));
    o.y = f2b(b2f(cv.y) + b2f(sv.y));
    o.z = f2b(b2f(cv.z) + b2f(sv.z));
    o.w = f2b(b2f(cv.w) + b2f(sv.w));
    ((ushort4*)out)[orow * 64 + c4] = o;
}

// temporal attention over T=5 (bf16 q/k/v; o written in-place over q).
__global__ __launch_bounds__(256) void mha_time(
    unsigned short* __restrict__ q, const unsigned short* __restrict__ k,
    const unsigned short* __restrict__ v)
{
    const int tid = threadIdx.x;
    const int grp = tid >> 5, c = tid & 31;
    long pair = (long)blockIdx.x * 8 + grp;   // BN*HH pairs
    int h = (int)(pair & 7);
    long bn = pair >> 3;
    const float scale = 0.17677669529663687f;
    float qv[TT], kv[TT], vv[TT];
    long r[TT];
#pragma unroll
    for (int t = 0; t < TT; ++t) {
        r[t] = ((long)t * BN + bn) * 256 + h * 32 + c;
        qv[t] = b2f(q[r[t]]); kv[t] = b2f(k[r[t]]); vv[t] = b2f(v[r[t]]);
    }
    float s[TT][TT];
#pragma unroll
    for (int t = 0; t < TT; ++t)
#pragma unroll
        for (int u = 0; u < TT; ++u) {
            float p = qv[t] * kv[u];
#pragma unroll
            for (int m = 16; m >= 1; m >>= 1) p += __shfl_xor(p, m, 64);
            s[t][u] = p * scale;
        }
#pragma unroll
    for (int t = 0; t < TT; ++t) {
        float mx = s[t][0];
#pragma unroll
        for (int u = 1; u < TT; ++u) mx = fmaxf(mx, s[t][u]);
        float sm = 0.f;
#pragma unroll
        for (int u = 0; u < TT; ++u) { s[t][u] = expf(s[t][u] - mx); sm += s[t][u]; }
        float inv = 1.f / sm;
        float o = 0.f;
#pragma unroll
        for (int u = 0; u < TT; ++u) o += s[t][u] * vv[u];
        q[r[t]] = f2b(o * inv);
    }
}

// seq(bf16) = LayerNorm(seq + res(bf16)) * g + b; one wave per row
__global__ __launch_bounds__(256) void ln_residual(
    unsigned short* __restrict__ seq, const unsigned short* __restrict__ res,
    const float* __restrict__ g, const float* __restrict__ b)
{
    const int wave = threadIdx.x >> 6, lane = threadIdx.x & 63;
    long row = (long)blockIdx.x * 4 + wave;
    const ushort4 s4 = *(const ushort4*)&seq[row * 256 + lane * 4];
    const ushort4 r4 = *(const ushort4*)&res[row * 256 + lane * 4];
    float x[4] = { b2f(s4.x) + b2f(r4.x), b2f(s4.y) + b2f(r4.y),
                   b2f(s4.z) + b2f(r4.z), b2f(s4.w) + b2f(r4.w) };
    float sum = x[0] + x[1] + x[2] + x[3];
#pragma unroll
    for (int m = 32; m >= 1; m >>= 1) sum += __shfl_xor(sum, m, 64);
    float mean = sum * (1.f / 256.f);
    float vs = 0.f;
#pragma unroll
    for (int i = 0; i < 4; ++i) { float dl = x[i] - mean; vs += dl * dl; }
#pragma unroll
    for (int m = 32; m >= 1; m >>= 1) vs += __shfl_xor(vs, m, 64);
    float inv = rsqrtf(vs * (1.f / 256.f) + 1e-5f);
    ushort4 o;
    o.x = f2b((x[0] - mean) * inv * g[lane * 4 + 0] + b[lane * 4 + 0]);
    o.y = f2b((x[1] - mean) * inv * g[lane * 4 + 1] + b[lane * 4 + 1]);
    o.z = f2b((x[2] - mean) * inv * g[lane * 4 + 2] + b[lane * 4 + 2]);
    o.w = f2b((x[3] - mean) * inv * g[lane * 4 + 3] + b[lane * 4 + 3]);
    *(ushort4*)&seq[row * 256 + lane * 4] = o;
}

// out[row][0..9] = seq[t=T-1 rows](bf16) @ W_out + b_out ; one block per row
__global__ __launch_bounds__(256) void final_out(
    const unsigned short* __restrict__ seq, const float* __restrict__ Wd,
    const float* __restrict__ bd, float* __restrict__ out)
{
    __shared__ float xs[256];
    long row = blockIdx.x;
    xs[threadIdx.x] = b2f(seq[((long)(TT - 1) * BN + row) * 256 + threadIdx.x]);
    __syncthreads();
    const int wv = threadIdx.x >> 6, lane = threadIdx.x & 63;
    for (int o = wv; o < NCLS; o += 4) {
        float p = 0.f;
#pragma unroll
        for (int i = 0; i < 4; ++i) {
            int kk = lane + 64 * i;
            p += xs[kk] * Wd[kk * NCLS + o];
        }
#pragma unroll
        for (int m = 32; m >= 1; m >>= 1) p += __shfl_xor(p, m, 64);
        if (lane == 0) out[row * NCLS + o] = p + bd[o];
    }
}

__global__ void fill_sentinel(float* __restrict__ out, int n) {
    int gid = blockIdx.x * blockDim.x + threadIdx.x;
    if (gid < n) out[gid] = 1.0e6f;
}

// =====================================================================
extern "C" void kernel_launch(void* const* d_in, const int* in_sizes, int n_in,
                              void* d_out, int out_size, void* d_ws, size_t ws_size,
                              hipStream_t stream) {
    const float* xseq  = (const float*)d_in[0];
    const int*   eidx  = (const int*)d_in[1];
    const float* eattr = (const float*)d_in[2];
    const float* W_node = (const float*)d_in[3];
    const float* b_node = (const float*)d_in[4];
    const float* W_edge = (const float*)d_in[5];
    const float* b_edge = (const float*)d_in[6];
    const float* Wq = (const float*)d_in[7];  const float* bq = (const float*)d_in[8];
    const float* Wk = (const float*)d_in[9];  const float* bk = (const float*)d_in[10];
    const float* Wv = (const float*)d_in[11]; const float* bv = (const float*)d_in[12];
    const float* Ws = (const float*)d_in[13]; const float* bs = (const float*)d_in[14];
    const float* Wqkv = (const float*)d_in[15]; const float* bqkv = (const float*)d_in[16];
    const float* Wo = (const float*)d_in[17];   const float* bo = (const float*)d_in[18];
    const float* W1 = (const float*)d_in[19];   const float* b1 = (const float*)d_in[20];
    const float* W2 = (const float*)d_in[21];   const float* b2 = (const float*)d_in[22];
    const float* g_ln1 = (const float*)d_in[23]; const float* b_ln1 = (const float*)d_in[24];
    const float* g_ln2 = (const float*)d_in[25]; const float* b_ln2 = (const float*)d_in[26];
    const float* W_out = (const float*)d_in[27]; const float* b_out = (const float*)d_in[28];
    float* out = (float*)d_out;

    // ---- workspace layout ----
    const long SZ = (long)NM * DD;            // 20,971,520 elements
    unsigned short* Abf = (unsigned short*)d_ws;     // seq activations bf16 (40MB)
    unsigned short* Zu  = Abf + SZ;                  // Z region: 3*SZ ushorts (120MB)
    unsigned short* Zq = Zu;                 // q -> conv out (in-place)
    unsigned short* Zk = Zu + SZ;            // k -> skip / residual / Hid
    unsigned short* Zv = Zu + 2 * SZ;        // v
    unsigned short* resB = Zk;               // Wo-out residual bf16 (40MB, over dead k)
    unsigned short* Hid = Zu + SZ;           // FFN hidden bf16 [MR][2048] (64MB)
    unsigned short* res2B = Zu + SZ + (long)MR * FFD;  // FFN residual bf16 [MR][256] (8MB)
    // weights region after Z:
    unsigned short* WX = Zu + 3 * SZ;
    unsigned short* xbf = WX;                             // 81920*64
    unsigned short* wtN = xbf + (long)NM * FIN;           // [256][64]
    unsigned short* wtQ = wtN + 256 * 64;
    unsigned short* wtK = wtQ + 65536;
    unsigned short* wtV = wtK + 65536;
    unsigned short* wtS = wtV + 65536;
    unsigned short* wtQKV = wtS + 65536;                  // 3 * [768][256]
    unsigned short* wtO = wtQKV + 3L * 768 * 256;         // 3 * [256][256]
    unsigned short* wtW1 = wtO + 3L * 65536;              // 3 * [2048][256]
    unsigned short* wtW2 = wtW1 + 3L * 2048 * 256;        // 3 * [256][2048]
    // CSR region
    int* cnt  = (int*)(wtW2 + 3L * 256 * 2048);
    int* coff = cnt + NM;                                 // NM+1
    int* cfil = coff + NM + 1;
    int* csr  = cfil + NM;                                // NE ints
    char* wend = (char*)(csr + NE);
    const size_t need = (size_t)(wend - (char*)d_ws);
    if (ws_size < need) {
        fill_sentinel<<<dim3((out_size + 255) / 256), dim3(256), 0, stream>>>(out, out_size);
        return;
    }

    dim3 blk(256);
    dim3 tb(32, 8);

    // ---- prologue: convert weights (fp32 [K][N] -> bf16 [N][K]) and x ----
    xconvert<<<dim3((unsigned)((long)NM * FIN / 4 / 256)), blk, 0, stream>>>(xseq, xbf, (long)NM * FIN / 4);
    wtrans<<<dim3(DD / 32, FIN / 32), tb, 0, stream>>>(W_node, wtN, FIN, DD);
    wtrans<<<dim3(DD / 32, DD / 32), tb, 0, stream>>>(Wq, wtQ, DD, DD);
    wtrans<<<dim3(DD / 32, DD / 32), tb, 0, stream>>>(Wk, wtK, DD, DD);
    wtrans<<<dim3(DD / 32, DD / 32), tb, 0, stream>>>(Wv, wtV, DD, DD);
    wtrans<<<dim3(DD / 32, DD / 32), tb, 0, stream>>>(Ws, wtS, DD, DD);
    for (int l = 0; l < 3; ++l) {
        wtrans<<<dim3(768 / 32, DD / 32), tb, 0, stream>>>(Wqkv + (long)l * DD * 768, wtQKV + (long)l * 768 * 256, DD, 768);
        wtrans<<<dim3(DD / 32, DD / 32), tb, 0, stream>>>(Wo + (long)l * DD * DD, wtO + (long)l * 65536, DD, DD);
        wtrans<<<dim3(FFD / 32, DD / 32), tb, 0, stream>>>(W1 + (long)l * DD * FFD, wtW1 + (long)l * 2048 * 256, DD, FFD);
        wtrans<<<dim3(DD / 32, FFD / 32), tb, 0, stream>>>(W2 + (long)l * FFD * DD, wtW2 + (long)l * 256 * 2048, FFD, DD);
    }

    // ---- CSR build (independent of GEMMs) ----
    csr_init<<<dim3((NM + 255) / 256), blk, 0, stream>>>(cnt, cfil);
    csr_count<<<dim3((unsigned)(NE / 256)), blk, 0, stream>>>(eidx, cnt);
    csr_scan<<<dim3(1), dim3(1024), 0, stream>>>(cnt, coff);
    csr_scatter<<<dim3((unsigned)(NE / 256)), blk, 0, stream>>>(eidx, coff, cfil, csr);

    // ---- stage 1: h, q/k/v, fused conv, skip, transpose+add ----
    gemm_mfma<false, true><<<dim3(NM / 128, DD / 128), blk, 0, stream>>>(
        xbf, FIN, wtN, b_node, Abf, DD, FIN);
    gemm_mfma<false, true><<<dim3(NM / 128, DD / 128), blk, 0, stream>>>(
        Abf, DD, wtQ, bq, Zq, DD, DD);
    gemm_mfma<false, true><<<dim3(NM / 128, DD / 128), blk, 0, stream>>>(
        Abf, DD, wtK, bk, Zk, DD, DD);
    gemm_mfma<false, true><<<dim3(NM / 128, DD / 128), blk, 0, stream>>>(
        Abf, DD, wtV, bv, Zv, DD, DD);
    conv_fused<<<dim3(NM / 4), blk, 0, stream>>>(
        Zq, Zk, Zv, eidx, eattr, W_edge, b_edge, coff, csr);
    gemm_mfma<false, true><<<dim3(NM / 128, DD / 128), blk, 0, stream>>>(
        Abf, DD, wtS, bs, Zk, DD, DD);                  // skip over dead k
    transpose_add<<<dim3(NM * 64 / 256), blk, 0, stream>>>(Zq, Zk, Abf);

    // ---- stage 2: 3 temporal transformer encoder layers ----
    for (int l = 0; l < 3; ++l) {
        const unsigned short* wql = wtQKV + (long)l * 768 * 256;
        const float* bl = bqkv + (long)l * 768;
        gemm_mfma<false, true><<<dim3(NM / 128, DD / 128), blk, 0, stream>>>(
            Abf, DD, wql + 0 * 256 * 256, bl + 0, Zq, DD, DD);
        gemm_mfma<false, true><<<dim3(NM / 128, DD / 128), blk, 0, stream>>>(
            Abf, DD, wql + 1L * 256 * 256, bl + 256, Zk, DD, DD);
        gemm_mfma<false, true><<<dim3(NM / 128, DD / 128), blk, 0, stream>>>(
            Abf, DD, wql + 2L * 256 * 256, bl + 512, Zv, DD, DD);
        mha_time<<<dim3(BN * HH / 8), blk, 0, stream>>>(Zq, Zk, Zv);
        gemm_mfma<false, true><<<dim3(NM / 128, DD / 128), blk, 0, stream>>>(
            Zq, DD, wtO + (long)l * 65536, bo + (long)l * DD, resB, DD, DD);
        ln_residual<<<dim3(NM / 4), blk, 0, stream>>>(Abf, resB, g_ln1 + l * DD, b_ln1 + l * DD);
        for (int mr = 0; mr < NM / MR; ++mr) {
            const long r0 = (long)mr * MR;
            gemm_mfma<true, true><<<dim3(MR / 128, FFD / 128), blk, 0, stream>>>(
                Abf + r0 * DD, DD, wtW1 + (long)l * 2048 * 256, b1 + (long)l * FFD, Hid, FFD, DD);
            gemm_mfma<false, true><<<dim3(MR / 128, DD / 128), blk, 0, stream>>>(
                Hid, FFD, wtW2 + (long)l * 256 * 2048, b2 + (long)l * DD, res2B, DD, FFD);
            ln_residual<<<dim3(MR / 4), blk, 0, stream>>>(
                Abf + r0 * DD, res2B, g_ln2 + l * DD, b_ln2 + l * DD);
        }
    }

    // ---- output head ----
    final_out<<<dim3(BN), blk, 0, stream>>>(Abf, W_out, b_out, out);
}

// Round 7
// 2544.345 us; speedup vs baseline: 8.6909x; 1.0027x over previous
//
#include <hip/hip_runtime.h>
#include <math.h>

// ---- problem constants ----
#define BB   8
#define TT   5
#define NN   2048
#define FIN  64
#define EE   32768
#define DD   256
#define HH   8
#define FFD  2048
#define NCLS 10
#define GG   (BB*TT)        // 40 graphs
#define BN   (BB*NN)        // 16384
#define NM   (GG*NN)        // 81920 rows (= TT*BN)
#define NE   ((long)GG*EE)  // 1310720 edges

#define MR        16384           // rows per FFN chunk (5 chunks)

typedef __attribute__((ext_vector_type(8))) short short8;
typedef __attribute__((ext_vector_type(4))) float f32x4;

// ---- bf16 helpers (RNE) ----
__device__ __forceinline__ unsigned short f2b(float f) {
    unsigned u = __float_as_uint(f);
    u = (u + 0x7fffu + ((u >> 16) & 1u)) >> 16;
    return (unsigned short)u;
}
__device__ __forceinline__ float b2f(unsigned short b) {
    return __uint_as_float(((unsigned)b) << 16);
}

// async global->LDS, 16B per lane (dest must be wave-uniform base + lane*16)
__device__ __forceinline__ void gload_lds16(const void* g, void* l) {
    __builtin_amdgcn_global_load_lds(
        (__attribute__((address_space(1))) void*)g,
        (__attribute__((address_space(3))) void*)l, 16, 0, 0);
}

// =====================================================================
// Weight transpose+convert: in fp32 [K][N] row-major -> out bf16 [N][K]
// =====================================================================
__global__ void wtrans(const float* __restrict__ in, unsigned short* __restrict__ out,
                       int K, int N) {
    __shared__ float t[32][33];
    const int n0 = blockIdx.x * 32, k0 = blockIdx.y * 32;
    const int tx = threadIdx.x, ty = threadIdx.y;
    for (int i = ty; i < 32; i += 8) t[i][tx] = in[(long)(k0 + i) * N + n0 + tx];
    __syncthreads();
    for (int i = ty; i < 32; i += 8)
        out[(long)(n0 + i) * K + k0 + tx] = f2b(t[tx][i]);
}

// fp32 -> bf16 elementwise (n4 float4 groups)
__global__ void xconvert(const float* __restrict__ in, unsigned short* __restrict__ out, long n4) {
    long gid = (long)blockIdx.x * blockDim.x + threadIdx.x;
    if (gid >= n4) return;
    float4 v = ((const float4*)in)[gid];
    ushort4 o;
    o.x = f2b(v.x); o.y = f2b(v.y); o.z = f2b(v.z); o.w = f2b(v.w);
    ((ushort4*)out)[gid] = o;
}

// pack 3 bias vectors of 256 into one 768 buffer
__global__ void pack3(const float* __restrict__ a, const float* __restrict__ b,
                      const float* __restrict__ c, float* __restrict__ o) {
    int i = threadIdx.x;
    o[i] = a[i]; o[256 + i] = b[i]; o[512 + i] = c[i];
}

// =====================================================================
// bf16 MFMA GEMM (m97 structure + XCD swizzle):
// C[M x N] = A[M x K] @ W[K x N] + bias
// A bf16 row-major (lda), WT = W^T bf16 [N][K], C fp32 or bf16 (ldc).
// 128x128 tile, BK=32, 256 threads = 4 waves (2x2), 16x16x32 MFMA.
// =====================================================================
template <bool RELU, bool OUTBF>
__global__ __launch_bounds__(256) void gemm_mfma(
    const unsigned short* __restrict__ A, int lda,
    const unsigned short* __restrict__ WT,
    const float* __restrict__ bias,
    void* __restrict__ Cv, int ldc, int K)
{
    __shared__ unsigned short As[128 * 32];
    __shared__ unsigned short Bs[128 * 32];
    const int tid = threadIdx.x;
    const int wid = tid >> 6, lane = tid & 63;
    const int wm = wid >> 1, wn = wid & 1;
    // XCD-chunked bijective swizzle: each XCD owns an M-chunk x all N,
    // y fastest within chunk (A-panel read once per XCD; W panels L2-hot).
    const int gx = gridDim.x, gy = gridDim.y;
    int bx = blockIdx.x, by = blockIdx.y;
    if ((gx & 7) == 0) {
        const int lbid = bx + gx * by;
        const int xcd = lbid & 7;
        const int i = lbid >> 3;
        const int CX = gx >> 3;
        bx = xcd * CX + i / gy;
        by = i - (i / gy) * gy;
    }
    const long row0 = (long)bx * 128;
    const long col0 = (long)by * 128;
    const int srow = tid >> 2;            // 0..63 (two row-blocks of 64)
    const int scol = (tid & 3) * 8;       // 0,8,16,24 (elements)
    const int kb = (lane >> 4) * 8;
    const int fr = lane & 15;
    f32x4 acc[4][4] = {};
    const unsigned short* Ag = &A[(row0 + srow) * (long)lda + scol];
    const unsigned short* Bg = &WT[(col0 + srow) * (long)K + scol];
    unsigned short* Al = &As[srow * 32 + scol];
    unsigned short* Bl = &Bs[srow * 32 + scol];
    for (int k0 = 0; k0 < K; k0 += 32) {
        __syncthreads();
        gload_lds16(Ag + k0, Al);
        gload_lds16(Ag + (long)64 * lda + k0, Al + 64 * 32);
        gload_lds16(Bg + k0, Bl);
        gload_lds16(Bg + (long)64 * K + k0, Bl + 64 * 32);
        __syncthreads();
        short8 af[4], bfr[4];
#pragma unroll
        for (int mf = 0; mf < 4; ++mf)
            af[mf] = *(const short8*)&As[(wm * 64 + mf * 16 + fr) * 32 + kb];
#pragma unroll
        for (int nf = 0; nf < 4; ++nf)
            bfr[nf] = *(const short8*)&Bs[(wn * 64 + nf * 16 + fr) * 32 + kb];
#pragma unroll
        for (int mf = 0; mf < 4; ++mf)
#pragma unroll
            for (int nf = 0; nf < 4; ++nf)
                acc[mf][nf] = __builtin_amdgcn_mfma_f32_16x16x32_bf16(
                    af[mf], bfr[nf], acc[mf][nf], 0, 0, 0);
    }
    const int fq = lane >> 4;
#pragma unroll
    for (int nf = 0; nf < 4; ++nf) {
        const long col = col0 + wn * 64 + nf * 16 + fr;
        const float bv = bias[col];
#pragma unroll
        for (int mf = 0; mf < 4; ++mf) {
#pragma unroll
            for (int i = 0; i < 4; ++i) {
                const long r = row0 + wm * 64 + mf * 16 + fq * 4 + i;
                float vv = acc[mf][nf][i] + bv;
                if (RELU) vv = fmaxf(vv, 0.f);
                if (OUTBF) ((unsigned short*)Cv)[r * ldc + col] = f2b(vv);
                else       ((float*)Cv)[r * ldc + col] = vv;
            }
        }
    }
}

// =====================================================================
// CSR build: edges grouped by global target row tf = g*NN + tgt
// =====================================================================
__global__ void csr_init(int* __restrict__ cnt, int* __restrict__ fill) {
    int gid = blockIdx.x * blockDim.x + threadIdx.x;
    if (gid < NM) { cnt[gid] = 0; fill[gid] = 0; }
}

__global__ void csr_count(const int* __restrict__ eidx, int* __restrict__ cnt) {
    long el = (long)blockIdx.x * blockDim.x + threadIdx.x;
    if (el >= NE) return;
    int g = (int)(el >> 15), e = (int)(el & (EE - 1));
    int tgt = eidx[((long)g * 2 + 1) * EE + e];
    atomicAdd(&cnt[g * NN + tgt], 1);
}

// single-block exclusive scan over NM counts (1024 threads x 80 each)
__global__ __launch_bounds__(1024) void csr_scan(const int* __restrict__ cnt, int* __restrict__ off) {
    __shared__ int part[1024];
    const int t = threadIdx.x;
    const int base = t * (NM / 1024);
    int s = 0;
    for (int i = 0; i < NM / 1024; ++i) s += cnt[base + i];
    part[t] = s;
    __syncthreads();
    for (int d = 1; d < 1024; d <<= 1) {
        int v = (t >= d) ? part[t - d] : 0;
        __syncthreads();
        part[t] += v;
        __syncthreads();
    }
    int run = (t == 0) ? 0 : part[t - 1];
    for (int i = 0; i < NM / 1024; ++i) { off[base + i] = run; run += cnt[base + i]; }
    if (t == 1023) off[NM] = run;
}

__global__ void csr_scatter(const int* __restrict__ eidx, const int* __restrict__ off,
                            int* __restrict__ fill, int* __restrict__ csr) {
    long el = (long)blockIdx.x * blockDim.x + threadIdx.x;
    if (el >= NE) return;
    int g = (int)(el >> 15), e = (int)(el & (EE - 1));
    int tgt = eidx[((long)g * 2 + 1) * EE + e];
    int tf = g * NN + tgt;
    int pos = atomicAdd(&fill[tf], 1);
    csr[off[tf] + pos] = (int)el;
}

// =====================================================================
// Fused TransformerConv on interleaved qkv [NM][768]: one wave per target
// node. Linearity decomposition: alpha = (q.k + qb_h + sum_j ea_j*qW_h[j])/sqC;
// out = (acc + b_edge*s + sum_j W_j*t_j)/s, t_j = sum_e a_e ea_j.
// Plain exp (scores |alpha| << 1 by construction) -> no serial rescale chain.
// Writes conv output (bf16) OVER the q slice.
// =====================================================================
__global__ __launch_bounds__(256) void conv_fused(
    unsigned short* __restrict__ Z,
    const int* __restrict__ eidx, const float* __restrict__ eattr,
    const float* __restrict__ W_edge, const float* __restrict__ b_edge,
    const int* __restrict__ off, const int* __restrict__ csr)
{
    const int tid = threadIdx.x;
    const int wave = tid >> 6, lane = tid & 63;
    // bijective XCD swizzle: 20480 blocks -> each XCD gets 2560 contiguous (5 graphs)
    const int bid = (blockIdx.x & 7) * (NM / 4 / 8) + (blockIdx.x >> 3);
    const long tf = (long)bid * 4 + wave;
    const int d0 = lane * 4;
    unsigned short* qrow = &Z[tf * 768];
    const ushort4 q4 = *(const ushort4*)&qrow[d0];
    const float q0 = b2f(q4.x), q1 = b2f(q4.y), q2 = b2f(q4.z), q3 = b2f(q4.w);
    const float be0 = b_edge[d0], be1 = b_edge[d0 + 1],
                be2 = b_edge[d0 + 2], be3 = b_edge[d0 + 3];
    float w0[6], w1r[6], w2r[6], w3r[6];
#pragma unroll
    for (int j2 = 0; j2 < 6; ++j2) {
        const float* wp = &W_edge[j2 * 256 + d0];
        w0[j2] = wp[0]; w1r[j2] = wp[1]; w2r[j2] = wp[2]; w3r[j2] = wp[3];
    }
    // per-head precompute: qb = q.b_edge (head), qw[j] = q.W_edge[j] (head)
    float qb = q0 * be0 + q1 * be1 + q2 * be2 + q3 * be3;
    float qw[6];
#pragma unroll
    for (int j2 = 0; j2 < 6; ++j2)
        qw[j2] = q0 * w0[j2] + q1 * w1r[j2] + q2 * w2r[j2] + q3 * w3r[j2];
#pragma unroll
    for (int mm = 1; mm <= 4; mm <<= 1) {
        qb += __shfl_xor(qb, mm, 64);
#pragma unroll
        for (int j2 = 0; j2 < 6; ++j2) qw[j2] += __shfl_xor(qw[j2], mm, 64);
    }
    const float scale = 0.17677669529663687f;  // 1/sqrt(32)
    float s = 0.f, a0 = 0.f, a1 = 0.f, a2 = 0.f, a3 = 0.f;
    float t0 = 0.f, t1 = 0.f, t2 = 0.f, t3 = 0.f, t4 = 0.f, t5 = 0.f;
    const int jb = off[tf], je = off[tf + 1];
    ushort4 kc, vc; float eac[6];
    if (jb < je) {
        const int el = csr[jb];
        const int g = el >> 15, e = el & (EE - 1);
        const int src = eidx[((long)g * 2) * EE + e];
        const long sf = (long)g * NN + src;
        kc = *(const ushort4*)&Z[sf * 768 + 256 + d0];
        vc = *(const ushort4*)&Z[sf * 768 + 512 + d0];
#pragma unroll
        for (int t = 0; t < 6; ++t) eac[t] = eattr[(long)el * 6 + t];
    }
    for (int j = jb; j < je; ++j) {
        ushort4 kn, vn; float ean[6];
        if (j + 1 < je) {  // prefetch next edge (wave-uniform branch)
            const int el = csr[j + 1];
            const int g = el >> 15, e = el & (EE - 1);
            const int src = eidx[((long)g * 2) * EE + e];
            const long sf = (long)g * NN + src;
            kn = *(const ushort4*)&Z[sf * 768 + 256 + d0];
            vn = *(const ushort4*)&Z[sf * 768 + 512 + d0];
#pragma unroll
            for (int t = 0; t < 6; ++t) ean[t] = eattr[(long)el * 6 + t];
        }
        float p = q0 * b2f(kc.x) + q1 * b2f(kc.y) + q2 * b2f(kc.z) + q3 * b2f(kc.w);
        p += __shfl_xor(p, 1, 64);
        p += __shfl_xor(p, 2, 64);
        p += __shfl_xor(p, 4, 64);   // 8-lane group = one head (32 dims)
        float alpha = p + qb;
        alpha += eac[0] * qw[0] + eac[1] * qw[1] + eac[2] * qw[2]
               + eac[3] * qw[3] + eac[4] * qw[4] + eac[5] * qw[5];
        const float a = __expf(alpha * scale);
        s += a;
        a0 += a * b2f(vc.x); a1 += a * b2f(vc.y);
        a2 += a * b2f(vc.z); a3 += a * b2f(vc.w);
        t0 += a * eac[0]; t1 += a * eac[1]; t2 += a * eac[2];
        t3 += a * eac[3]; t4 += a * eac[4]; t5 += a * eac[5];
        kc = kn; vc = vn;
#pragma unroll
        for (int t = 0; t < 6; ++t) eac[t] = ean[t];
    }
    const float inv = (s > 0.f) ? 1.f / s : 0.f;
    float o0 = a0 + be0 * s, o1 = a1 + be1 * s, o2 = a2 + be2 * s, o3 = a3 + be3 * s;
    o0 += w0[0]*t0 + w0[1]*t1 + w0[2]*t2 + w0[3]*t3 + w0[4]*t4 + w0[5]*t5;
    o1 += w1r[0]*t0 + w1r[1]*t1 + w1r[2]*t2 + w1r[3]*t3 + w1r[4]*t4 + w1r[5]*t5;
    o2 += w2r[0]*t0 + w2r[1]*t1 + w2r[2]*t2 + w2r[3]*t3 + w2r[4]*t4 + w2r[5]*t5;
    o3 += w3r[0]*t0 + w3r[1]*t1 + w3r[2]*t2 + w3r[3]*t3 + w3r[4]*t4 + w3r[5]*t5;
    ushort4 o;
    o.x = f2b(o0 * inv); o.y = f2b(o1 * inv);
    o.z = f2b(o2 * inv); o.w = f2b(o3 * inv);
    *(ushort4*)&qrow[d0] = o;
}

// seq(bf16, [t*BN+b*N+n][256]) = conv(q-slice of Z) + skip(k-slice of Z)
__global__ void transpose_add(const unsigned short* __restrict__ Z,
                              unsigned short* __restrict__ out) {
    long gid = (long)blockIdx.x * blockDim.x + threadIdx.x;  // NM*64 ushort4s
    long row = gid >> 6;
    int c4 = (int)(gid & 63);
    int n = (int)(row % NN);
    int bt = (int)(row / NN);
    int t = bt % TT, b = bt / TT;
    long orow = (long)t * BN + (long)b * NN + n;
    ushort4 cv = ((const ushort4*)&Z[row * 768])[c4];
    ushort4 sv = ((const ushort4*)&Z[row * 768 + 256])[c4];
    ushort4 o;
    o.x = f2b(b2f(cv.x) + b2f(sv.x));
    o.y = f2b(b2f(cv.y) + b2f(sv.y));
    o.z = f2b(b2f(cv.z) + b2f(sv.z));
    o.w = f2b(b2f(cv.w) + b2f(sv.w));
    ((ushort4*)out)[orow * 64 + c4] = o;
}

// temporal attention over T=5 on interleaved qkv [NM][768]; o over q-slice.
__global__ __launch_bounds__(256) void mha_time(unsigned short* __restrict__ Z)
{
    const int tid = threadIdx.x;
    const int grp = tid >> 5, c = tid & 31;
    long pair = (long)blockIdx.x * 8 + grp;   // BN*HH pairs
    int h = (int)(pair & 7);
    long bn = pair >> 3;
    const float scale = 0.17677669529663687f;
    float qv[TT], kv[TT], vv[TT];
    long r[TT];
#pragma unroll
    for (int t = 0; t < TT; ++t) {
        r[t] = ((long)t * BN + bn) * 768 + h * 32 + c;
        qv[t] = b2f(Z[r[t]]); kv[t] = b2f(Z[r[t] + 256]); vv[t] = b2f(Z[r[t] + 512]);
    }
    float s[TT][TT];
#pragma unroll
    for (int t = 0; t < TT; ++t)
#pragma unroll
        for (int u = 0; u < TT; ++u) {
            float p = qv[t] * kv[u];
#pragma unroll
            for (int m = 16; m >= 1; m >>= 1) p += __shfl_xor(p, m, 64);
            s[t][u] = p * scale;
        }
#pragma unroll
    for (int t = 0; t < TT; ++t) {
        float mx = s[t][0];
#pragma unroll
        for (int u = 1; u < TT; ++u) mx = fmaxf(mx, s[t][u]);
        float sm = 0.f;
#pragma unroll
        for (int u = 0; u < TT; ++u) { s[t][u] = expf(s[t][u] - mx); sm += s[t][u]; }
        float inv = 1.f / sm;
        float o = 0.f;
#pragma unroll
        for (int u = 0; u < TT; ++u) o += s[t][u] * vv[u];
        Z[r[t]] = f2b(o * inv);
    }
}

// seq(bf16) = LayerNorm(seq + res(bf16, row-stride rstride)) * g + b
__global__ __launch_bounds__(256) void ln_residual(
    unsigned short* __restrict__ seq, const unsigned short* __restrict__ res,
    int rstride, const float* __restrict__ g, const float* __restrict__ b)
{
    const int wave = threadIdx.x >> 6, lane = threadIdx.x & 63;
    long row = (long)blockIdx.x * 4 + wave;
    const ushort4 s4 = *(const ushort4*)&seq[row * 256 + lane * 4];
    const ushort4 r4 = *(const ushort4*)&res[row * (long)rstride + lane * 4];
    float x[4] = { b2f(s4.x) + b2f(r4.x), b2f(s4.y) + b2f(r4.y),
                   b2f(s4.z) + b2f(r4.z), b2f(s4.w) + b2f(r4.w) };
    float sum = x[0] + x[1] + x[2] + x[3];
#pragma unroll
    for (int m = 32; m >= 1; m >>= 1) sum += __shfl_xor(sum, m, 64);
    float mean = sum * (1.f / 256.f);
    float vs = 0.f;
#pragma unroll
    for (int i = 0; i < 4; ++i) { float dl = x[i] - mean; vs += dl * dl; }
#pragma unroll
    for (int m = 32; m >= 1; m >>= 1) vs += __shfl_xor(vs, m, 64);
    float inv = rsqrtf(vs * (1.f / 256.f) + 1e-5f);
    ushort4 o;
    o.x = f2b((x[0] - mean) * inv * g[lane * 4 + 0] + b[lane * 4 + 0]);
    o.y = f2b((x[1] - mean) * inv * g[lane * 4 + 1] + b[lane * 4 + 1]);
    o.z = f2b((x[2] - mean) * inv * g[lane * 4 + 2] + b[lane * 4 + 2]);
    o.w = f2b((x[3] - mean) * inv * g[lane * 4 + 3] + b[lane * 4 + 3]);
    *(ushort4*)&seq[row * 256 + lane * 4] = o;
}

// out[row][0..9] = seq[t=T-1 rows](bf16) @ W_out + b_out ; one block per row
__global__ __launch_bounds__(256) void final_out(
    const unsigned short* __restrict__ seq, const float* __restrict__ Wd,
    const float* __restrict__ bd, float* __restrict__ out)
{
    __shared__ float xs[256];
    long row = blockIdx.x;
    xs[threadIdx.x] = b2f(seq[((long)(TT - 1) * BN + row) * 256 + threadIdx.x]);
    __syncthreads();
    const int wv = threadIdx.x >> 6, lane = threadIdx.x & 63;
    for (int o = wv; o < NCLS; o += 4) {
        float p = 0.f;
#pragma unroll
        for (int i = 0; i < 4; ++i) {
            int kk = lane + 64 * i;
            p += xs[kk] * Wd[kk * NCLS + o];
        }
#pragma unroll
        for (int m = 32; m >= 1; m >>= 1) p += __shfl_xor(p, m, 64);
        if (lane == 0) out[row * NCLS + o] = p + bd[o];
    }
}

__global__ void fill_sentinel(float* __restrict__ out, int n) {
    int gid = blockIdx.x * blockDim.x + threadIdx.x;
    if (gid < n) out[gid] = 1.0e6f;
}

// =====================================================================
extern "C" void kernel_launch(void* const* d_in, const int* in_sizes, int n_in,
                              void* d_out, int out_size, void* d_ws, size_t ws_size,
                              hipStream_t stream) {
    const float* xseq  = (const float*)d_in[0];
    const int*   eidx  = (const int*)d_in[1];
    const float* eattr = (const float*)d_in[2];
    const float* W_node = (const float*)d_in[3];
    const float* b_node = (const float*)d_in[4];
    const float* W_edge = (const float*)d_in[5];
    const float* b_edge = (const float*)d_in[6];
    const float* Wq = (const float*)d_in[7];  const float* bq = (const float*)d_in[8];
    const float* Wk = (const float*)d_in[9];  const float* bk = (const float*)d_in[10];
    const float* Wv = (const float*)d_in[11]; const float* bv = (const float*)d_in[12];
    const float* Ws = (const float*)d_in[13]; const float* bs = (const float*)d_in[14];
    const float* Wqkv = (const float*)d_in[15]; const float* bqkv = (const float*)d_in[16];
    const float* Wo = (const float*)d_in[17];   const float* bo = (const float*)d_in[18];
    const float* W1 = (const float*)d_in[19];   const float* b1 = (const float*)d_in[20];
    const float* W2 = (const float*)d_in[21];   const float* b2 = (const float*)d_in[22];
    const float* g_ln1 = (const float*)d_in[23]; const float* b_ln1 = (const float*)d_in[24];
    const float* g_ln2 = (const float*)d_in[25]; const float* b_ln2 = (const float*)d_in[26];
    const float* W_out = (const float*)d_in[27]; const float* b_out = (const float*)d_in[28];
    float* out = (float*)d_out;

    // ---- workspace layout ----
    const long SZ = (long)NM * DD;            // 20,971,520 elements
    unsigned short* Abf = (unsigned short*)d_ws;     // seq activations bf16 (40MB)
    unsigned short* Zu  = Abf + SZ;                  // Z region: 3*SZ ushorts (120MB)
    // Z holds interleaved qkv [NM][768]; later (FFN) reused flat:
    unsigned short* Hid = Zu;                        // FFN hidden bf16 [MR][2048] (64MB)
    unsigned short* res2B = Zu + (long)MR * FFD;     // FFN residual bf16 [MR][256] (8MB)
    // weights region after Z:
    unsigned short* WX = Zu + 3 * SZ;
    unsigned short* xbf = WX;                             // 81920*64
    unsigned short* wtN = xbf + (long)NM * FIN;           // [256][64]
    unsigned short* wtQ = wtN + 256 * 64;                 // [768][256] stacked q,k,v
    unsigned short* wtK = wtQ + 65536;
    unsigned short* wtV = wtK + 65536;
    unsigned short* wtS = wtV + 65536;
    unsigned short* wtQKV = wtS + 65536;                  // 3 * [768][256]
    unsigned short* wtO = wtQKV + 3L * 768 * 256;         // 3 * [256][256]
    unsigned short* wtW1 = wtO + 3L * 65536;              // 3 * [2048][256]
    unsigned short* wtW2 = wtW1 + 3L * 2048 * 256;        // 3 * [256][2048]
    // CSR region
    int* cnt  = (int*)(wtW2 + 3L * 256 * 2048);
    int* coff = cnt + NM;                                 // NM+1
    int* cfil = coff + NM + 1;
    int* csr  = cfil + NM;                                // NE ints
    float* qkvb = (float*)(csr + NE);                     // 768 packed bias
    char* wend = (char*)(qkvb + 768);
    const size_t need = (size_t)(wend - (char*)d_ws);
    if (ws_size < need) {
        fill_sentinel<<<dim3((out_size + 255) / 256), dim3(256), 0, stream>>>(out, out_size);
        return;
    }

    dim3 blk(256);
    dim3 tb(32, 8);

    // ---- prologue: convert weights (fp32 [K][N] -> bf16 [N][K]) and x ----
    xconvert<<<dim3((unsigned)((long)NM * FIN / 4 / 256)), blk, 0, stream>>>(xseq, xbf, (long)NM * FIN / 4);
    wtrans<<<dim3(DD / 32, FIN / 32), tb, 0, stream>>>(W_node, wtN, FIN, DD);
    wtrans<<<dim3(DD / 32, DD / 32), tb, 0, stream>>>(Wq, wtQ, DD, DD);
    wtrans<<<dim3(DD / 32, DD / 32), tb, 0, stream>>>(Wk, wtK, DD, DD);
    wtrans<<<dim3(DD / 32, DD / 32), tb, 0, stream>>>(Wv, wtV, DD, DD);
    wtrans<<<dim3(DD / 32, DD / 32), tb, 0, stream>>>(Ws, wtS, DD, DD);
    pack3<<<dim3(1), blk, 0, stream>>>(bq, bk, bv, qkvb);
    for (int l = 0; l < 3; ++l) {
        wtrans<<<dim3(768 / 32, DD / 32), tb, 0, stream>>>(Wqkv + (long)l * DD * 768, wtQKV + (long)l * 768 * 256, DD, 768);
        wtrans<<<dim3(DD / 32, DD / 32), tb, 0, stream>>>(Wo + (long)l * DD * DD, wtO + (long)l * 65536, DD, DD);
        wtrans<<<dim3(FFD / 32, DD / 32), tb, 0, stream>>>(W1 + (long)l * DD * FFD, wtW1 + (long)l * 2048 * 256, DD, FFD);
        wtrans<<<dim3(DD / 32, FFD / 32), tb, 0, stream>>>(W2 + (long)l * FFD * DD, wtW2 + (long)l * 256 * 2048, FFD, DD);
    }

    // ---- CSR build (independent of GEMMs) ----
    csr_init<<<dim3((NM + 255) / 256), blk, 0, stream>>>(cnt, cfil);
    csr_count<<<dim3((unsigned)(NE / 256)), blk, 0, stream>>>(eidx, cnt);
    csr_scan<<<dim3(1), dim3(1024), 0, stream>>>(cnt, coff);
    csr_scatter<<<dim3((unsigned)(NE / 256)), blk, 0, stream>>>(eidx, coff, cfil, csr);

    // ---- stage 1: h -> Abf; qkv (N=768) -> Z; conv; skip -> k-slice; add ----
    gemm_mfma<false, true><<<dim3(NM / 128, DD / 128), blk, 0, stream>>>(
        xbf, FIN, wtN, b_node, Abf, DD, FIN);
    gemm_mfma<false, true><<<dim3(NM / 128, 768 / 128), blk, 0, stream>>>(
        Abf, DD, wtQ, qkvb, Zu, 768, DD);
    conv_fused<<<dim3(NM / 4), blk, 0, stream>>>(
        Zu, eidx, eattr, W_edge, b_edge, coff, csr);
    gemm_mfma<false, true><<<dim3(NM / 128, DD / 128), blk, 0, stream>>>(
        Abf, DD, wtS, bs, (void*)(Zu + 256), 768, DD);    // skip into dead k-slice
    transpose_add<<<dim3(NM * 64 / 256), blk, 0, stream>>>(Zu, Abf);

    // ---- stage 2: 3 temporal transformer encoder layers ----
    for (int l = 0; l < 3; ++l) {
        gemm_mfma<false, true><<<dim3(NM / 128, 768 / 128), blk, 0, stream>>>(
            Abf, DD, wtQKV + (long)l * 768 * 256, bqkv + (long)l * 768, Zu, 768, DD);
        mha_time<<<dim3(BN * HH / 8), blk, 0, stream>>>(Zu);
        gemm_mfma<false, true><<<dim3(NM / 128, DD / 128), blk, 0, stream>>>(
            Zu, 768, wtO + (long)l * 65536, bo + (long)l * DD, (void*)(Zu + 512), 768, DD);
        ln_residual<<<dim3(NM / 4), blk, 0, stream>>>(
            Abf, Zu + 512, 768, g_ln1 + l * DD, b_ln1 + l * DD);
        for (int mr = 0; mr < NM / MR; ++mr) {
            const long r0 = (long)mr * MR;
            gemm_mfma<true, true><<<dim3(MR / 128, FFD / 128), blk, 0, stream>>>(
                Abf + r0 * DD, DD, wtW1 + (long)l * 2048 * 256, b1 + (long)l * FFD, Hid, FFD, DD);
            gemm_mfma<false, true><<<dim3(MR / 128, DD / 128), blk, 0, stream>>>(
                Hid, FFD, wtW2 + (long)l * 256 * 2048, b2 + (long)l * DD, res2B, DD, FFD);
            ln_residual<<<dim3(MR / 4), blk, 0, stream>>>(
                Abf + r0 * DD, res2B, DD, g_ln2 + l * DD, b_ln2 + l * DD);
        }
    }

    // ---- output head ----
    final_out<<<dim3(BN), blk, 0, stream>>>(Abf, W_out, b_out, out);
}